// Round 19
// baseline (111.730 us; speedup 1.0000x reference)
//
#include <hip/hip_runtime.h>
#include <hip/hip_bf16.h>
#include <math.h>

#define B_ 4
#define N_ 512
#define D_ 128
#define O_ 64
#define H_ 4

#define SELU_SCALE 1.0507009873554805f
#define SELU_SCALE_ALPHA 1.7580993408473766f  // scale * alpha

typedef short  short8 __attribute__((ext_vector_type(8)));
typedef float  f32x4  __attribute__((ext_vector_type(4)));

__device__ __forceinline__ ushort bf16rne(float f) {
    uint u = __float_as_uint(f);
    return (ushort)((u + 0x7fffu + ((u >> 16) & 1u)) >> 16);
}
__device__ __forceinline__ void bf16split(float f, ushort& h, ushort& l) {
    h = bf16rne(f);
    float hf = __uint_as_float(((uint)h) << 16);
    l = bf16rne(f - hf);
}

// ---------------------------------------------------------------------------
// prep_frags (validated r3-r18): four fragment tensors by blockIdx range.
// ---------------------------------------------------------------------------
__global__ __launch_bounds__(256) void prep_frags(
    const float* __restrict__ x, const float* __restrict__ PW,
    const float* __restrict__ NW,
    ushort* __restrict__ xf, ushort* __restrict__ xfT,
    ushort* __restrict__ pwf, ushort* __restrict__ nwf)
{
    const int bid = blockIdx.x;
    const int tid = threadIdx.x;

    if (bid < 128) {
        const int t  = bid * 256 + tid;
        const int jg = t >> 4;
        const int dc = t & 15;
        const int jf = jg >> 4;
        const int kc = dc >> 2, q = dc & 3;
        const int lane = (jg & 15) | (q << 4);

        const f32x4 v0 = *(const f32x4*)&x[t * 8];
        const f32x4 v1 = *(const f32x4*)&x[t * 8 + 4];
        float vv[8] = {v0[0], v0[1], v0[2], v0[3], v1[0], v1[1], v1[2], v1[3]};
        short8 h8, l8;
        #pragma unroll
        for (int e = 0; e < 8; ++e) {
            ushort h, l; bf16split(vv[e], h, l);
            h8[e] = (short)h; l8[e] = (short)l;
        }
        const int fi = (jf * 4 + kc) * 2;
        *(short8*)&xf[(size_t)fi * 512 + lane * 8]       = h8;
        *(short8*)&xf[(size_t)(fi + 1) * 512 + lane * 8] = l8;
    } else if (bid < 256) {
        const int t    = (bid - 128) * 256 + tid;
        const int lane = t & 63, fr = t >> 6;
        const int d0 = fr & 7, kc = (fr >> 3) & 15, b = fr >> 7;
        const int l15 = lane & 15, q4 = lane >> 4;
        short8 h8, l8;
        #pragma unroll
        for (int e = 0; e < 8; ++e) {
            const float v = x[(size_t)((b * 512) + kc * 32 + q4 * 8 + e) * 128 + d0 * 16 + l15];
            ushort h, l; bf16split(v, h, l);
            h8[e] = (short)h; l8[e] = (short)l;
        }
        *(short8*)&xfT[(size_t)(fr * 2) * 512 + lane * 8]     = h8;
        *(short8*)&xfT[(size_t)(fr * 2 + 1) * 512 + lane * 8] = l8;
    } else if (bid < 272) {
        const int t    = (bid - 256) * 256 + tid;
        const int lane = t & 63, fr = t >> 6;
        const int o0 = fr & 3, kc = fr >> 2;
        const int l15 = lane & 15, q4 = lane >> 4;
        short8 h8, l8;
        #pragma unroll
        for (int e = 0; e < 8; ++e) {
            const int kk = kc * 32 + q4 * 8 + e;
            const int d = kk & 127, h = kk >> 7;
            const float v = PW[(d * 4 + h) * O_ + o0 * 16 + l15];
            ushort hh, ll; bf16split(v, hh, ll);
            h8[e] = (short)hh; l8[e] = (short)ll;
        }
        *(short8*)&pwf[(size_t)(fr * 2) * 512 + lane * 8]     = h8;
        *(short8*)&pwf[(size_t)(fr * 2 + 1) * 512 + lane * 8] = l8;
    } else {
        const int t    = (bid - 272) * 256 + tid;
        const int lane = t & 63, fr = t >> 6;
        const int o0 = fr & 3, kc = fr >> 2;
        const int l15 = lane & 15, q4 = lane >> 4;
        short8 h8, l8;
        #pragma unroll
        for (int e = 0; e < 8; ++e) {
            const float v = NW[(kc * 32 + q4 * 8 + e) * O_ + o0 * 16 + l15];
            ushort hh, ll; bf16split(v, hh, ll);
            h8[e] = (short)hh; l8[e] = (short)ll;
        }
        *(short8*)&nwf[(size_t)(fr * 2) * 512 + lane * 8]     = h8;
        *(short8*)&nwf[(size_t)(fr * 2 + 1) * 512 + lane * 8] = l8;
    }
}

#define SP_STRIDE 520

// compiler-proof 16B global load: UNIFORM SGPR base + per-lane VGPR byte
// offset + imm (r11 post-mortem: base must be wave-uniform for "s").
#define GLD(dst, off, base, IMM)                                     \
    asm volatile("global_load_dwordx4 %0, %1, %2 offset:" #IMM       \
                 : "=v"(dst) : "v"(off), "s"(base))

#define MFMA_BF16(A, Bv, C) __builtin_amdgcn_mfma_f32_16x16x32_bf16(A, Bv, C, 0, 0, 0)

// ---------------------------------------------------------------------------
// attn_scores: r18 phase-1 structure preserved exactly (passed, 97 us).
// r19: (a) phase-3 xfT loads converted to the proven GLD + counted-vmcnt
// double-buffer (they were plain loads -> compiler sank them -> serialized
// L2 latency, the r5-r9 failure mode); (b) dual am chains in the epilogue.
// ---------------------------------------------------------------------------
__global__ __launch_bounds__(256)
__attribute__((amdgpu_waves_per_eu(2, 2)))
void attn_scores(
    const float* __restrict__ x,
    const ushort* __restrict__ xf,
    const ushort* __restrict__ xfT,
    const float* __restrict__ Wa,
    const float* __restrict__ ba,
    const float* __restrict__ AW,
    ushort* __restrict__ X1h, ushort* __restrict__ X1l)
{
    __shared__ float sAmp[8 * SP_STRIDE];   // [wo*4+q4][j] logit partials; aliased as sXp
    __shared__ float sP[4 * SP_STRIDE];     // probs [h][j]

    const int tid  = threadIdx.x;
    const int i    = blockIdx.x;
    const int bB   = blockIdx.y;
    const int lane = tid & 63;
    const int w    = tid >> 6;
    const int l15  = lane & 15;
    const int q4   = lane >> 4;
    const int wo   = w >> 1;                // o-half
    const int wj   = w & 1;                 // j-half
    const f32x4 z = {0.f, 0.f, 0.f, 0.f};

    const ushort* xfb = xf + (size_t)(bB * 32) * 4096;     // block-uniform base
    const uint voff  = (uint)lane * 16u + (uint)wj * 131072u;
    const uint voff2 = voff + 4096u;

    // ---- prologue: issue this wave's tile-0 loads immediately ----
    short8 Bh0[4], Bl0[4], Bh1[4], Bl1[4];
    GLD(Bh0[0], voff,  xfb, 0);    GLD(Bl0[0], voff,  xfb, 1024);
    GLD(Bh0[1], voff,  xfb, 2048); GLD(Bl0[1], voff,  xfb, 3072);
    GLD(Bh0[2], voff2, xfb, 0);    GLD(Bl0[2], voff2, xfb, 1024);
    GLD(Bh0[3], voff2, xfb, 2048); GLD(Bl0[3], voff2, xfb, 3072);

    // ---- A-frags: two G2^T rows, o = wo*32+l15 and +16, in regs ----
    const float* xi = x + ((size_t)bB * N_ + i) * D_;
    const int oa0 = wo * 32 + l15, oa1 = oa0 + 16;
    short8 gh0[4], gl0[4], gh1[4], gl1[4];
    #pragma unroll
    for (int kc = 0; kc < 4; ++kc) {
        const int d0 = kc * 32 + q4 * 8;
        const f32x4 a0 = *(const f32x4*)&xi[d0];
        const f32x4 a1 = *(const f32x4*)&xi[d0 + 4];
        #pragma unroll
        for (int e = 0; e < 8; ++e) {
            const float xe2 = 2.f * ((e < 4) ? a0[e & 3] : a1[e & 3]);
            ushort h, l;
            bf16split(xe2 * Wa[(d0 + e) * O_ + oa0], h, l);
            gh0[kc][e] = (short)h; gl0[kc][e] = (short)l;
            bf16split(xe2 * Wa[(d0 + e) * O_ + oa1], h, l);
            gh1[kc][e] = (short)h; gl1[kc][e] = (short)l;
        }
    }

    // ---- epilogue constants: 8 o's per lane (4 per row) ----
    const int oc0 = wo * 32 + q4 * 4, oc1 = oc0 + 16;
    const f32x4 awA0 = *(const f32x4*)&AW[(oc0 + 0) * H_];
    const f32x4 awA1 = *(const f32x4*)&AW[(oc0 + 1) * H_];
    const f32x4 awA2 = *(const f32x4*)&AW[(oc0 + 2) * H_];
    const f32x4 awA3 = *(const f32x4*)&AW[(oc0 + 3) * H_];
    const f32x4 awB0 = *(const f32x4*)&AW[(oc1 + 0) * H_];
    const f32x4 awB1 = *(const f32x4*)&AW[(oc1 + 1) * H_];
    const f32x4 awB2 = *(const f32x4*)&AW[(oc1 + 2) * H_];
    const f32x4 awB3 = *(const f32x4*)&AW[(oc1 + 3) * H_];
    const f32x4 b2A = { 2.f * ba[oc0], 2.f * ba[oc0 + 1], 2.f * ba[oc0 + 2], 2.f * ba[oc0 + 3] };
    const f32x4 b2B = { 2.f * ba[oc1], 2.f * ba[oc1 + 1], 2.f * ba[oc1 + 2], 2.f * ba[oc1 + 3] };

// One tile T: issue next loads, counted wait, 24 MFMA in two chains, tanh+am
// epilogue (DUAL am chains for ILP), row store. No barriers.
#define SCORE_STEP(BHc, BLc, BHn, BLn, T)                                           \
    {                                                                               \
        if ((T) < 15) {                                                             \
            const ushort* bp = xfb + (size_t)((T) + 1) * 4096;                      \
            GLD(BHn[0], voff,  bp, 0);    GLD(BLn[0], voff,  bp, 1024);             \
            GLD(BHn[1], voff,  bp, 2048); GLD(BLn[1], voff,  bp, 3072);             \
            GLD(BHn[2], voff2, bp, 0);    GLD(BLn[2], voff2, bp, 1024);             \
            GLD(BHn[3], voff2, bp, 2048); GLD(BLn[3], voff2, bp, 3072);             \
            asm volatile("s_waitcnt vmcnt(16)" ::: "memory");                       \
        } else {                                                                    \
            asm volatile("s_waitcnt vmcnt(0)" ::: "memory");                        \
        }                                                                           \
        __builtin_amdgcn_sched_barrier(0);                                          \
        f32x4 accA = b2A, accB = b2B;                                               \
        _Pragma("unroll")                                                           \
        for (int kc = 0; kc < 4; ++kc) {                                            \
            accA = MFMA_BF16(gh0[kc], BHc[kc], accA);                               \
            accB = MFMA_BF16(gh1[kc], BHc[kc], accB);                               \
            accA = MFMA_BF16(gl0[kc], BHc[kc], accA);                               \
            accB = MFMA_BF16(gl1[kc], BHc[kc], accB);                               \
            accA = MFMA_BF16(gh0[kc], BLc[kc], accA);                               \
            accB = MFMA_BF16(gh1[kc], BLc[kc], accB);                               \
        }                                                                           \
        f32x4 amA, amB;                                                             \
        {                                                                           \
            const float e0 = __expf(accA[0]);                                       \
            const float e1 = __expf(accA[1]);                                       \
            const float e2 = __expf(accA[2]);                                       \
            const float e3 = __expf(accA[3]);                                       \
            const float f0 = __expf(accB[0]);                                       \
            const float f1 = __expf(accB[1]);                                       \
            const float f2 = __expf(accB[2]);                                       \
            const float f3 = __expf(accB[3]);                                       \
            amA  = fmaf(-2.f, __builtin_amdgcn_rcpf(e0 + 1.f), 1.f) * awA0;         \
            amB  = fmaf(-2.f, __builtin_amdgcn_rcpf(f0 + 1.f), 1.f) * awB0;         \
            amA += fmaf(-2.f, __builtin_amdgcn_rcpf(e1 + 1.f), 1.f) * awA1;         \
            amB += fmaf(-2.f, __builtin_amdgcn_rcpf(f1 + 1.f), 1.f) * awB1;         \
            amA += fmaf(-2.f, __builtin_amdgcn_rcpf(e2 + 1.f), 1.f) * awA2;         \
            amB += fmaf(-2.f, __builtin_amdgcn_rcpf(f2 + 1.f), 1.f) * awB2;         \
            amA += fmaf(-2.f, __builtin_amdgcn_rcpf(e3 + 1.f), 1.f) * awA3;         \
            amB += fmaf(-2.f, __builtin_amdgcn_rcpf(f3 + 1.f), 1.f) * awB3;         \
        }                                                                           \
        f32x4 am = amA + amB;                                                       \
        _Pragma("unroll")                                                           \
        for (int k = 0; k < 4; ++k) {                                               \
            am[k] += __shfl_xor(am[k], 16);                                         \
            am[k] += __shfl_xor(am[k], 32);                                         \
        }                                                                           \
        const float amsel = (q4 == 0) ? am[0] : (q4 == 1) ? am[1]                   \
                          : (q4 == 2) ? am[2] : am[3];                              \
        sAmp[(wo * 4 + q4) * SP_STRIDE + (wj * 16 + (T)) * 16 + l15] = amsel;       \
    }

    for (int t = 0; t < 7; ++t) {
        SCORE_STEP(Bh0, Bl0, Bh1, Bl1, 2 * t)
        SCORE_STEP(Bh1, Bl1, Bh0, Bl0, 2 * t + 1)
    }
    SCORE_STEP(Bh0, Bl0, Bh1, Bl1, 14)
    SCORE_STEP(Bh1, Bl1, Bh0, Bl0, 15)
#undef SCORE_STEP
    __syncthreads();   // all logit rows visible (drains vmcnt too)

    // ---- phase-3 prefetch setup; c=0 loads issued NOW, hidden by softmax ----
    // addr bytes = (bB*16 + w*4 + c)*16384 + nf*2048 + split*1024 + lane*16
    short8 XA[16], XB[16];
    uint offs[8];
    #pragma unroll
    for (int nf = 0; nf < 8; ++nf)
        offs[nf] = (uint)lane * 16u + (uint)w * 65536u + (uint)nf * 2048u;
    {
        const ushort* bp3 = xfT + (size_t)(bB * 16) * 8192;   // c = 0 base (ushorts)
        #pragma unroll
        for (int nf = 0; nf < 8; ++nf) {
            GLD(XA[2 * nf],     offs[nf], bp3, 0);
            GLD(XA[2 * nf + 1], offs[nf], bp3, 1024);
        }
    }

    // ---- phase 2: softmax over j, one wave per head; 2-way combine ----
    {
        const int h = w;
        float v[8];
        float m = -INFINITY;
        #pragma unroll
        for (int k = 0; k < 8; ++k) {
            const int j = k * 64 + lane;
            v[k] = sAmp[h * SP_STRIDE + j] + sAmp[(4 + h) * SP_STRIDE + j];
            m = fmaxf(m, v[k]);
        }
        #pragma unroll
        for (int s = 32; s >= 1; s >>= 1) m = fmaxf(m, __shfl_xor(m, s));
        float l = 0.f;
        #pragma unroll
        for (int k = 0; k < 8; ++k) { v[k] = __expf(v[k] - m); l += v[k]; }
        #pragma unroll
        for (int s = 32; s >= 1; s >>= 1) l += __shfl_xor(l, s);
        const float rinv = 1.f / l;
        #pragma unroll
        for (int k = 0; k < 8; ++k) sP[h * SP_STRIDE + k * 64 + lane] = v[k] * rinv;
    }
    __syncthreads();

    // ---- phase 3: x1 = P.X via MFMA, GLD-pipelined at c granularity ----
    f32x4 acc2[8];
    #pragma unroll
    for (int nf = 0; nf < 8; ++nf) acc2[nf] = z;

#define P3_STEP(XC, XN, C)                                                          \
    {                                                                               \
        if ((C) < 3) {                                                              \
            const ushort* bp3 = xfT + (size_t)(bB * 16 + (C) + 1) * 8192;           \
            _Pragma("unroll")                                                       \
            for (int nf = 0; nf < 8; ++nf) {                                        \
                GLD(XN[2 * nf],     offs[nf], bp3, 0);                              \
                GLD(XN[2 * nf + 1], offs[nf], bp3, 1024);                           \
            }                                                                       \
        }                                                                           \
        const int kc = w * 4 + (C);                                                 \
        const int base = (l15 & 3) * SP_STRIDE + kc * 32 + q4 * 8;                  \
        const f32x4 p0 = *(const f32x4*)&sP[base];                                  \
        const f32x4 p1 = *(const f32x4*)&sP[base + 4];                              \
        float pv[8] = {p0[0], p0[1], p0[2], p0[3], p1[0], p1[1], p1[2], p1[3]};     \
        short8 pah, pal;                                                            \
        _Pragma("unroll")                                                           \
        for (int e = 0; e < 8; ++e) {                                               \
            ushort h, l; bf16split(pv[e], h, l);                                    \
            pah[e] = (short)h; pal[e] = (short)l;                                   \
        }                                                                           \
        if ((C) < 3) { asm volatile("s_waitcnt vmcnt(16)" ::: "memory"); }          \
        else         { asm volatile("s_waitcnt vmcnt(0)"  ::: "memory"); }          \
        __builtin_amdgcn_sched_barrier(0);                                          \
        _Pragma("unroll")                                                           \
        for (int nf = 0; nf < 8; ++nf) {                                            \
            acc2[nf] = MFMA_BF16(pah, XC[2 * nf],     acc2[nf]);                    \
            acc2[nf] = MFMA_BF16(pal, XC[2 * nf],     acc2[nf]);                    \
            acc2[nf] = MFMA_BF16(pah, XC[2 * nf + 1], acc2[nf]);                    \
        }                                                                           \
    }

    P3_STEP(XA, XB, 0)
    P3_STEP(XB, XA, 1)
    P3_STEP(XA, XB, 2)
    P3_STEP(XB, XA, 3)
#undef P3_STEP

    float* sXp = sAmp;   // reuse logit rows as [16][128] wave partials
    if (q4 == 0) {
        #pragma unroll
        for (int nf = 0; nf < 8; ++nf)
            #pragma unroll
            for (int r = 0; r < 4; ++r)
                sXp[(w * 4 + r) * 128 + nf * 16 + l15] = acc2[nf][r];
    }
    __syncthreads();

    // ---- phase 3b: reduce wave partials, split, store X1 ----
    {
        const int kap = tid * 2;
        const size_t row = (size_t)bB * N_ + i;
        float v0 = 0.f, v1 = 0.f;
        #pragma unroll
        for (int ww = 0; ww < 4; ++ww) {
            v0 += sXp[(ww * 4 + (kap >> 7)) * 128 + (kap & 127)];
            v1 += sXp[(ww * 4 + ((kap + 1) >> 7)) * 128 + ((kap + 1) & 127)];
        }
        ushort h0, l0, h1, l1;
        bf16split(v0, h0, l0);
        bf16split(v1, h1, l1);
        *(uint*)&X1h[row * 512 + kap] = (uint)h0 | ((uint)h1 << 16);
        *(uint*)&X1l[row * 512 + kap] = (uint)l0 | ((uint)l1 << 16);
    }
}

// ---------------------------------------------------------------------------
// proj_y_part: y = x1.PW' + x.NW + biases (MFMA) + per-block BN partial sums.
// ---------------------------------------------------------------------------
__global__ __launch_bounds__(256) void proj_y_part(
    const ushort* __restrict__ X1h, const ushort* __restrict__ X1l,
    const ushort* __restrict__ xf,
    const ushort* __restrict__ pwf, const ushort* __restrict__ nwf,
    const float* __restrict__ PWb, const float* __restrict__ NWb,
    float* __restrict__ y, float* __restrict__ part)
{
    const int tid = threadIdx.x, bid = blockIdx.x;
    const int lane = tid & 63, w = tid >> 6;
    const int l15 = lane & 15, q4 = lane >> 4;
    const int bi0 = bid * 16;
    const int b = bi0 >> 9, ig = (bi0 >> 4) & 31;

    f32x4 acc = {0.f, 0.f, 0.f, 0.f};
    #pragma unroll
    for (int kc = 0; kc < 16; ++kc) {
        const size_t arow = (size_t)(bi0 + l15) * 512 + kc * 32 + q4 * 8;
        const short8 ah = *(const short8*)&X1h[arow];
        const short8 al = *(const short8*)&X1l[arow];
        const int f3 = (kc * 4 + w) * 2;
        const short8 bhv = *(const short8*)&pwf[(size_t)f3 * 512 + lane * 8];
        const short8 blv = *(const short8*)&pwf[(size_t)(f3 + 1) * 512 + lane * 8];
        acc = MFMA_BF16(ah, bhv, acc);
        acc = MFMA_BF16(al, bhv, acc);
        acc = MFMA_BF16(ah, blv, acc);
    }
    #pragma unroll
    for (int kc = 0; kc < 4; ++kc) {
        const size_t fi = ((size_t)(b * 32 + ig) * 4 + kc) * 2;
        const short8 ah = *(const short8*)&xf[fi * 512 + lane * 8];
        const short8 al = *(const short8*)&xf[(fi + 1) * 512 + lane * 8];
        const int f4 = (kc * 4 + w) * 2;
        const short8 bhv = *(const short8*)&nwf[(size_t)f4 * 512 + lane * 8];
        const short8 blv = *(const short8*)&nwf[(size_t)(f4 + 1) * 512 + lane * 8];
        acc = MFMA_BF16(ah, bhv, acc);
        acc = MFMA_BF16(al, bhv, acc);
        acc = MFMA_BF16(ah, blv, acc);
    }
    const int oo = w * 16 + l15;
    const float bias = PWb[oo] + NWb[oo];
    float s = 0.f, sq = 0.f;
    #pragma unroll
    for (int r = 0; r < 4; ++r) {
        const float yv = acc[r] + bias;
        y[(size_t)(bi0 + q4 * 4 + r) * O_ + oo] = yv;
        s += yv; sq += yv * yv;
    }
    s  += __shfl_xor(s, 16);  s  += __shfl_xor(s, 32);
    sq += __shfl_xor(sq, 16); sq += __shfl_xor(sq, 32);
    if (q4 == 0) {
        part[bid * 256 + oo]       = s;
        part[bid * 256 + 128 + oo] = sq;
    }
}

// ---------------------------------------------------------------------------
// bn_apply_fused (validated r17/r18): redundant stats reduce + BN + SELU.
// ---------------------------------------------------------------------------
__global__ __launch_bounds__(256) void bn_apply_fused(
    float* __restrict__ y, const float* __restrict__ part,
    const float* __restrict__ gamma, const float* __restrict__ beta)
{
    __shared__ float sStats[128];
    const int tid = threadIdx.x, o = tid & 63, g = tid >> 6;

    float s = 0.f, sq = 0.f;
    #pragma unroll 4
    for (int k = 0; k < 32; ++k) {
        const int blk = g * 32 + k;
        s  += part[blk * 256 + o];
        sq += part[blk * 256 + 128 + o];
    }
    __shared__ float ls[4][64], lq[4][64];
    ls[g][o] = s; lq[g][o] = sq;
    __syncthreads();
    if (tid < 64) {
        const float inv = 1.f / 2048.f;
        const float ts = ls[0][tid] + ls[1][tid] + ls[2][tid] + ls[3][tid];
        const float tq = lq[0][tid] + lq[1][tid] + lq[2][tid] + lq[3][tid];
        const float mu  = ts * inv;
        const float var = tq * inv - mu * mu;
        const float rstd = rsqrtf(var + 1e-5f);
        const float sc = gamma[tid] * rstd;
        sStats[tid]      = sc;
        sStats[64 + tid] = beta[tid] - mu * sc;
    }
    __syncthreads();

    const int idx = blockIdx.x * 256 + tid;
    f32x4 v = *(f32x4*)&y[idx * 4];
    const int o0 = (idx * 4) & 63;
    #pragma unroll
    for (int k = 0; k < 4; ++k) {
        const float t = v[k] * sStats[o0 + k] + sStats[64 + o0 + k];
        v[k] = t > 0.f ? SELU_SCALE * t : SELU_SCALE_ALPHA * (__expf(t) - 1.f);
    }
    *(f32x4*)&y[idx * 4] = v;
}

extern "C" void kernel_launch(void* const* d_in, const int* in_sizes, int n_in,
                              void* d_out, int out_size, void* d_ws, size_t ws_size,
                              hipStream_t stream)
{
    (void)in_sizes; (void)n_in; (void)out_size; (void)ws_size;
    const float* x     = (const float*)d_in[0];
    const float* Wa    = (const float*)d_in[1];
    const float* ba    = (const float*)d_in[2];
    const float* AW    = (const float*)d_in[3];
    const float* PW    = (const float*)d_in[4];
    const float* PWb   = (const float*)d_in[5];
    const float* NW    = (const float*)d_in[6];
    const float* NWb   = (const float*)d_in[7];
    const float* gamma = (const float*)d_in[8];
    const float* beta  = (const float*)d_in[9];

    char* ws = (char*)d_ws;
    ushort* xf    = (ushort*)ws;                                   // 1 MB
    ushort* xfT   = (ushort*)(ws + (1 << 20));                     // 1 MB
    ushort* X1h   = (ushort*)(ws + (2 << 20));                     // 2 MB
    ushort* X1l   = (ushort*)(ws + (4 << 20));                     // 2 MB
    ushort* pwf   = (ushort*)(ws + (6 << 20));                     // 128 KB
    ushort* nwf   = (ushort*)(ws + (6 << 20) + (128 << 10));       // 32 KB
    float*  part  = (float*)(ws + (6 << 20) + (160 << 10));        // 128 KB
    float*  y     = (float*)d_out;

    prep_frags<<<276, 256, 0, stream>>>(x, PW, NW, xf, xfT, pwf, nwf);
    attn_scores<<<dim3(N_, B_), 256, 0, stream>>>(x, xf, xfT, Wa, ba, AW, X1h, X1l);
    proj_y_part<<<128, 256, 0, stream>>>(X1h, X1l, xf, pwf, nwf, PWb, NWb, y, part);
    bn_apply_fused<<<128, 256, 0, stream>>>(y, part, gamma, beta);
}

// Round 20
// 95.927 us; speedup vs baseline: 1.1647x; 1.1647x over previous
//
#include <hip/hip_runtime.h>
#include <hip/hip_bf16.h>
#include <math.h>

#define B_ 4
#define N_ 512
#define D_ 128
#define O_ 64
#define H_ 4

#define SELU_SCALE 1.0507009873554805f
#define SELU_SCALE_ALPHA 1.7580993408473766f  // scale * alpha

typedef short  short8 __attribute__((ext_vector_type(8)));
typedef float  f32x4  __attribute__((ext_vector_type(4)));

__device__ __forceinline__ ushort bf16rne(float f) {
    uint u = __float_as_uint(f);
    return (ushort)((u + 0x7fffu + ((u >> 16) & 1u)) >> 16);
}
__device__ __forceinline__ void bf16split(float f, ushort& h, ushort& l) {
    h = bf16rne(f);
    float hf = __uint_as_float(((uint)h) << 16);
    l = bf16rne(f - hf);
}

// ---------------------------------------------------------------------------
// prep_frags (validated r3-r19): four fragment tensors by blockIdx range.
// ---------------------------------------------------------------------------
__global__ __launch_bounds__(256) void prep_frags(
    const float* __restrict__ x, const float* __restrict__ PW,
    const float* __restrict__ NW,
    ushort* __restrict__ xf, ushort* __restrict__ xfT,
    ushort* __restrict__ pwf, ushort* __restrict__ nwf)
{
    const int bid = blockIdx.x;
    const int tid = threadIdx.x;

    if (bid < 128) {
        const int t  = bid * 256 + tid;
        const int jg = t >> 4;
        const int dc = t & 15;
        const int jf = jg >> 4;
        const int kc = dc >> 2, q = dc & 3;
        const int lane = (jg & 15) | (q << 4);

        const f32x4 v0 = *(const f32x4*)&x[t * 8];
        const f32x4 v1 = *(const f32x4*)&x[t * 8 + 4];
        float vv[8] = {v0[0], v0[1], v0[2], v0[3], v1[0], v1[1], v1[2], v1[3]};
        short8 h8, l8;
        #pragma unroll
        for (int e = 0; e < 8; ++e) {
            ushort h, l; bf16split(vv[e], h, l);
            h8[e] = (short)h; l8[e] = (short)l;
        }
        const int fi = (jf * 4 + kc) * 2;
        *(short8*)&xf[(size_t)fi * 512 + lane * 8]       = h8;
        *(short8*)&xf[(size_t)(fi + 1) * 512 + lane * 8] = l8;
    } else if (bid < 256) {
        const int t    = (bid - 128) * 256 + tid;
        const int lane = t & 63, fr = t >> 6;
        const int d0 = fr & 7, kc = (fr >> 3) & 15, b = fr >> 7;
        const int l15 = lane & 15, q4 = lane >> 4;
        short8 h8, l8;
        #pragma unroll
        for (int e = 0; e < 8; ++e) {
            const float v = x[(size_t)((b * 512) + kc * 32 + q4 * 8 + e) * 128 + d0 * 16 + l15];
            ushort h, l; bf16split(v, h, l);
            h8[e] = (short)h; l8[e] = (short)l;
        }
        *(short8*)&xfT[(size_t)(fr * 2) * 512 + lane * 8]     = h8;
        *(short8*)&xfT[(size_t)(fr * 2 + 1) * 512 + lane * 8] = l8;
    } else if (bid < 272) {
        const int t    = (bid - 256) * 256 + tid;
        const int lane = t & 63, fr = t >> 6;
        const int o0 = fr & 3, kc = fr >> 2;
        const int l15 = lane & 15, q4 = lane >> 4;
        short8 h8, l8;
        #pragma unroll
        for (int e = 0; e < 8; ++e) {
            const int kk = kc * 32 + q4 * 8 + e;
            const int d = kk & 127, h = kk >> 7;
            const float v = PW[(d * 4 + h) * O_ + o0 * 16 + l15];
            ushort hh, ll; bf16split(v, hh, ll);
            h8[e] = (short)hh; l8[e] = (short)ll;
        }
        *(short8*)&pwf[(size_t)(fr * 2) * 512 + lane * 8]     = h8;
        *(short8*)&pwf[(size_t)(fr * 2 + 1) * 512 + lane * 8] = l8;
    } else {
        const int t    = (bid - 272) * 256 + tid;
        const int lane = t & 63, fr = t >> 6;
        const int o0 = fr & 3, kc = fr >> 2;
        const int l15 = lane & 15, q4 = lane >> 4;
        short8 h8, l8;
        #pragma unroll
        for (int e = 0; e < 8; ++e) {
            const float v = NW[(kc * 32 + q4 * 8 + e) * O_ + o0 * 16 + l15];
            ushort hh, ll; bf16split(v, hh, ll);
            h8[e] = (short)hh; l8[e] = (short)ll;
        }
        *(short8*)&nwf[(size_t)(fr * 2) * 512 + lane * 8]     = h8;
        *(short8*)&nwf[(size_t)(fr * 2 + 1) * 512 + lane * 8] = l8;
    }
}

#define SP_STRIDE 520

// compiler-proof 16B global load: UNIFORM SGPR base + per-lane VGPR byte
// offset + imm (r11 post-mortem: base must be wave-uniform for "s").
#define GLD(dst, off, base, IMM)                                     \
    asm volatile("global_load_dwordx4 %0, %1, %2 offset:" #IMM       \
                 : "=v"(dst) : "v"(off), "s"(base))

#define MFMA_BF16(A, Bv, C) __builtin_amdgcn_mfma_f32_16x16x32_bf16(A, Bv, C, 0, 0, 0)

// ---------------------------------------------------------------------------
// attn_scores: r19 structure (passed, 94 us), ONE change: phase-1 drops the
// x-LO B-term (r19 post-mortem: kernel is L2-BW bound on B fragments; absmax
// headroom 0.0156 << 0.095 allows hi-only x in scores). B loads 8->4/tile
// (phase-1 L2 traffic HALVES), MFMA 24->16/tile. G keeps hi/lo (A-side,
// free). Phase 3 keeps full x hi+lo precision.
// ---------------------------------------------------------------------------
__global__ __launch_bounds__(256)
__attribute__((amdgpu_waves_per_eu(2, 2)))
void attn_scores(
    const float* __restrict__ x,
    const ushort* __restrict__ xf,
    const ushort* __restrict__ xfT,
    const float* __restrict__ Wa,
    const float* __restrict__ ba,
    const float* __restrict__ AW,
    ushort* __restrict__ X1h, ushort* __restrict__ X1l)
{
    __shared__ float sAmp[8 * SP_STRIDE];   // [wo*4+q4][j] logit partials; aliased as sXp
    __shared__ float sP[4 * SP_STRIDE];     // probs [h][j]

    const int tid  = threadIdx.x;
    const int i    = blockIdx.x;
    const int bB   = blockIdx.y;
    const int lane = tid & 63;
    const int w    = tid >> 6;
    const int l15  = lane & 15;
    const int q4   = lane >> 4;
    const int wo   = w >> 1;                // o-half
    const int wj   = w & 1;                 // j-half
    const f32x4 z = {0.f, 0.f, 0.f, 0.f};

    const ushort* xfb = xf + (size_t)(bB * 32) * 4096;     // block-uniform base
    const uint voff  = (uint)lane * 16u + (uint)wj * 131072u;
    const uint voff2 = voff + 4096u;

    // ---- prologue: issue this wave's tile-0 HI loads immediately ----
    short8 Bh0[4], Bh1[4];
    GLD(Bh0[0], voff,  xfb, 0);    GLD(Bh0[1], voff,  xfb, 2048);
    GLD(Bh0[2], voff2, xfb, 0);    GLD(Bh0[3], voff2, xfb, 2048);

    // ---- A-frags: two G2^T rows, o = wo*32+l15 and +16, in regs ----
    const float* xi = x + ((size_t)bB * N_ + i) * D_;
    const int oa0 = wo * 32 + l15, oa1 = oa0 + 16;
    short8 gh0[4], gl0[4], gh1[4], gl1[4];
    #pragma unroll
    for (int kc = 0; kc < 4; ++kc) {
        const int d0 = kc * 32 + q4 * 8;
        const f32x4 a0 = *(const f32x4*)&xi[d0];
        const f32x4 a1 = *(const f32x4*)&xi[d0 + 4];
        #pragma unroll
        for (int e = 0; e < 8; ++e) {
            const float xe2 = 2.f * ((e < 4) ? a0[e & 3] : a1[e & 3]);
            ushort h, l;
            bf16split(xe2 * Wa[(d0 + e) * O_ + oa0], h, l);
            gh0[kc][e] = (short)h; gl0[kc][e] = (short)l;
            bf16split(xe2 * Wa[(d0 + e) * O_ + oa1], h, l);
            gh1[kc][e] = (short)h; gl1[kc][e] = (short)l;
        }
    }

    // ---- epilogue constants: 8 o's per lane (4 per row) ----
    const int oc0 = wo * 32 + q4 * 4, oc1 = oc0 + 16;
    const f32x4 awA0 = *(const f32x4*)&AW[(oc0 + 0) * H_];
    const f32x4 awA1 = *(const f32x4*)&AW[(oc0 + 1) * H_];
    const f32x4 awA2 = *(const f32x4*)&AW[(oc0 + 2) * H_];
    const f32x4 awA3 = *(const f32x4*)&AW[(oc0 + 3) * H_];
    const f32x4 awB0 = *(const f32x4*)&AW[(oc1 + 0) * H_];
    const f32x4 awB1 = *(const f32x4*)&AW[(oc1 + 1) * H_];
    const f32x4 awB2 = *(const f32x4*)&AW[(oc1 + 2) * H_];
    const f32x4 awB3 = *(const f32x4*)&AW[(oc1 + 3) * H_];
    const f32x4 b2A = { 2.f * ba[oc0], 2.f * ba[oc0 + 1], 2.f * ba[oc0 + 2], 2.f * ba[oc0 + 3] };
    const f32x4 b2B = { 2.f * ba[oc1], 2.f * ba[oc1 + 1], 2.f * ba[oc1 + 2], 2.f * ba[oc1 + 3] };

// One tile T: issue next tile's 4 HI loads, counted wait, 16 MFMA in two
// chains, tanh+am epilogue (dual am chains), row store. No barriers.
#define SCORE_STEP(BHc, BHn, T)                                                     \
    {                                                                               \
        if ((T) < 15) {                                                             \
            const ushort* bp = xfb + (size_t)((T) + 1) * 4096;                      \
            GLD(BHn[0], voff,  bp, 0);    GLD(BHn[1], voff,  bp, 2048);             \
            GLD(BHn[2], voff2, bp, 0);    GLD(BHn[3], voff2, bp, 2048);             \
            asm volatile("s_waitcnt vmcnt(4)" ::: "memory");                        \
        } else {                                                                    \
            asm volatile("s_waitcnt vmcnt(0)" ::: "memory");                        \
        }                                                                           \
        __builtin_amdgcn_sched_barrier(0);                                          \
        f32x4 accA = b2A, accB = b2B;                                               \
        _Pragma("unroll")                                                           \
        for (int kc = 0; kc < 4; ++kc) {                                            \
            accA = MFMA_BF16(gh0[kc], BHc[kc], accA);                               \
            accB = MFMA_BF16(gh1[kc], BHc[kc], accB);                               \
            accA = MFMA_BF16(gl0[kc], BHc[kc], accA);                               \
            accB = MFMA_BF16(gl1[kc], BHc[kc], accB);                               \
        }                                                                           \
        f32x4 amA, amB;                                                             \
        {                                                                           \
            const float e0 = __expf(accA[0]);                                       \
            const float e1 = __expf(accA[1]);                                       \
            const float e2 = __expf(accA[2]);                                       \
            const float e3 = __expf(accA[3]);                                       \
            const float f0 = __expf(accB[0]);                                       \
            const float f1 = __expf(accB[1]);                                       \
            const float f2 = __expf(accB[2]);                                       \
            const float f3 = __expf(accB[3]);                                       \
            amA  = fmaf(-2.f, __builtin_amdgcn_rcpf(e0 + 1.f), 1.f) * awA0;         \
            amB  = fmaf(-2.f, __builtin_amdgcn_rcpf(f0 + 1.f), 1.f) * awB0;         \
            amA += fmaf(-2.f, __builtin_amdgcn_rcpf(e1 + 1.f), 1.f) * awA1;         \
            amB += fmaf(-2.f, __builtin_amdgcn_rcpf(f1 + 1.f), 1.f) * awB1;         \
            amA += fmaf(-2.f, __builtin_amdgcn_rcpf(e2 + 1.f), 1.f) * awA2;         \
            amB += fmaf(-2.f, __builtin_amdgcn_rcpf(f2 + 1.f), 1.f) * awB2;         \
            amA += fmaf(-2.f, __builtin_amdgcn_rcpf(e3 + 1.f), 1.f) * awA3;         \
            amB += fmaf(-2.f, __builtin_amdgcn_rcpf(f3 + 1.f), 1.f) * awB3;         \
        }                                                                           \
        f32x4 am = amA + amB;                                                       \
        _Pragma("unroll")                                                           \
        for (int k = 0; k < 4; ++k) {                                               \
            am[k] += __shfl_xor(am[k], 16);                                         \
            am[k] += __shfl_xor(am[k], 32);                                         \
        }                                                                           \
        const float amsel = (q4 == 0) ? am[0] : (q4 == 1) ? am[1]                   \
                          : (q4 == 2) ? am[2] : am[3];                              \
        sAmp[(wo * 4 + q4) * SP_STRIDE + (wj * 16 + (T)) * 16 + l15] = amsel;       \
    }

    for (int t = 0; t < 7; ++t) {
        SCORE_STEP(Bh0, Bh1, 2 * t)
        SCORE_STEP(Bh1, Bh0, 2 * t + 1)
    }
    SCORE_STEP(Bh0, Bh1, 14)
    SCORE_STEP(Bh1, Bh0, 15)
#undef SCORE_STEP
    __syncthreads();   // all logit rows visible

    // ---- phase-3 prefetch setup; c=0 loads issued NOW, hidden by softmax ----
    short8 XA[16], XB[16];
    uint offs[8];
    #pragma unroll
    for (int nf = 0; nf < 8; ++nf)
        offs[nf] = (uint)lane * 16u + (uint)w * 65536u + (uint)nf * 2048u;
    {
        const ushort* bp3 = xfT + (size_t)(bB * 16) * 8192;   // c = 0 base
        #pragma unroll
        for (int nf = 0; nf < 8; ++nf) {
            GLD(XA[2 * nf],     offs[nf], bp3, 0);
            GLD(XA[2 * nf + 1], offs[nf], bp3, 1024);
        }
    }

    // ---- phase 2: softmax over j, one wave per head; 2-way combine ----
    {
        const int h = w;
        float v[8];
        float m = -INFINITY;
        #pragma unroll
        for (int k = 0; k < 8; ++k) {
            const int j = k * 64 + lane;
            v[k] = sAmp[h * SP_STRIDE + j] + sAmp[(4 + h) * SP_STRIDE + j];
            m = fmaxf(m, v[k]);
        }
        #pragma unroll
        for (int s = 32; s >= 1; s >>= 1) m = fmaxf(m, __shfl_xor(m, s));
        float l = 0.f;
        #pragma unroll
        for (int k = 0; k < 8; ++k) { v[k] = __expf(v[k] - m); l += v[k]; }
        #pragma unroll
        for (int s = 32; s >= 1; s >>= 1) l += __shfl_xor(l, s);
        const float rinv = 1.f / l;
        #pragma unroll
        for (int k = 0; k < 8; ++k) sP[h * SP_STRIDE + k * 64 + lane] = v[k] * rinv;
    }
    __syncthreads();

    // ---- phase 3: x1 = P.X via MFMA, GLD-pipelined at c granularity ----
    f32x4 acc2[8];
    #pragma unroll
    for (int nf = 0; nf < 8; ++nf) acc2[nf] = z;

#define P3_STEP(XC, XN, C)                                                          \
    {                                                                               \
        if ((C) < 3) {                                                              \
            const ushort* bp3 = xfT + (size_t)(bB * 16 + (C) + 1) * 8192;           \
            _Pragma("unroll")                                                       \
            for (int nf = 0; nf < 8; ++nf) {                                        \
                GLD(XN[2 * nf],     offs[nf], bp3, 0);                              \
                GLD(XN[2 * nf + 1], offs[nf], bp3, 1024);                           \
            }                                                                       \
        }                                                                           \
        const int kc = w * 4 + (C);                                                 \
        const int base = (l15 & 3) * SP_STRIDE + kc * 32 + q4 * 8;                  \
        const f32x4 p0 = *(const f32x4*)&sP[base];                                  \
        const f32x4 p1 = *(const f32x4*)&sP[base + 4];                              \
        float pv[8] = {p0[0], p0[1], p0[2], p0[3], p1[0], p1[1], p1[2], p1[3]};     \
        short8 pah, pal;                                                            \
        _Pragma("unroll")                                                           \
        for (int e = 0; e < 8; ++e) {                                               \
            ushort h, l; bf16split(pv[e], h, l);                                    \
            pah[e] = (short)h; pal[e] = (short)l;                                   \
        }                                                                           \
        if ((C) < 3) { asm volatile("s_waitcnt vmcnt(16)" ::: "memory"); }          \
        else         { asm volatile("s_waitcnt vmcnt(0)"  ::: "memory"); }          \
        __builtin_amdgcn_sched_barrier(0);                                          \
        _Pragma("unroll")                                                           \
        for (int nf = 0; nf < 8; ++nf) {                                            \
            acc2[nf] = MFMA_BF16(pah, XC[2 * nf],     acc2[nf]);                    \
            acc2[nf] = MFMA_BF16(pal, XC[2 * nf],     acc2[nf]);                    \
            acc2[nf] = MFMA_BF16(pah, XC[2 * nf + 1], acc2[nf]);                    \
        }                                                                           \
    }

    P3_STEP(XA, XB, 0)
    P3_STEP(XB, XA, 1)
    P3_STEP(XA, XB, 2)
    P3_STEP(XB, XA, 3)
#undef P3_STEP

    float* sXp = sAmp;   // reuse logit rows as [16][128] wave partials
    if (q4 == 0) {
        #pragma unroll
        for (int nf = 0; nf < 8; ++nf)
            #pragma unroll
            for (int r = 0; r < 4; ++r)
                sXp[(w * 4 + r) * 128 + nf * 16 + l15] = acc2[nf][r];
    }
    __syncthreads();

    // ---- phase 3b: reduce wave partials, split, store X1 ----
    {
        const int kap = tid * 2;
        const size_t row = (size_t)bB * N_ + i;
        float v0 = 0.f, v1 = 0.f;
        #pragma unroll
        for (int ww = 0; ww < 4; ++ww) {
            v0 += sXp[(ww * 4 + (kap >> 7)) * 128 + (kap & 127)];
            v1 += sXp[(ww * 4 + ((kap + 1) >> 7)) * 128 + ((kap + 1) & 127)];
        }
        ushort h0, l0, h1, l1;
        bf16split(v0, h0, l0);
        bf16split(v1, h1, l1);
        *(uint*)&X1h[row * 512 + kap] = (uint)h0 | ((uint)h1 << 16);
        *(uint*)&X1l[row * 512 + kap] = (uint)l0 | ((uint)l1 << 16);
    }
}

// ---------------------------------------------------------------------------
// proj_y_part: y = x1.PW' + x.NW + biases (MFMA) + per-block BN partial sums.
// ---------------------------------------------------------------------------
__global__ __launch_bounds__(256) void proj_y_part(
    const ushort* __restrict__ X1h, const ushort* __restrict__ X1l,
    const ushort* __restrict__ xf,
    const ushort* __restrict__ pwf, const ushort* __restrict__ nwf,
    const float* __restrict__ PWb, const float* __restrict__ NWb,
    float* __restrict__ y, float* __restrict__ part)
{
    const int tid = threadIdx.x, bid = blockIdx.x;
    const int lane = tid & 63, w = tid >> 6;
    const int l15 = lane & 15, q4 = lane >> 4;
    const int bi0 = bid * 16;
    const int b = bi0 >> 9, ig = (bi0 >> 4) & 31;

    f32x4 acc = {0.f, 0.f, 0.f, 0.f};
    #pragma unroll
    for (int kc = 0; kc < 16; ++kc) {
        const size_t arow = (size_t)(bi0 + l15) * 512 + kc * 32 + q4 * 8;
        const short8 ah = *(const short8*)&X1h[arow];
        const short8 al = *(const short8*)&X1l[arow];
        const int f3 = (kc * 4 + w) * 2;
        const short8 bhv = *(const short8*)&pwf[(size_t)f3 * 512 + lane * 8];
        const short8 blv = *(const short8*)&pwf[(size_t)(f3 + 1) * 512 + lane * 8];
        acc = MFMA_BF16(ah, bhv, acc);
        acc = MFMA_BF16(al, bhv, acc);
        acc = MFMA_BF16(ah, blv, acc);
    }
    #pragma unroll
    for (int kc = 0; kc < 4; ++kc) {
        const size_t fi = ((size_t)(b * 32 + ig) * 4 + kc) * 2;
        const short8 ah = *(const short8*)&xf[fi * 512 + lane * 8];
        const short8 al = *(const short8*)&xf[(fi + 1) * 512 + lane * 8];
        const int f4 = (kc * 4 + w) * 2;
        const short8 bhv = *(const short8*)&nwf[(size_t)f4 * 512 + lane * 8];
        const short8 blv = *(const short8*)&nwf[(size_t)(f4 + 1) * 512 + lane * 8];
        acc = MFMA_BF16(ah, bhv, acc);
        acc = MFMA_BF16(al, bhv, acc);
        acc = MFMA_BF16(ah, blv, acc);
    }
    const int oo = w * 16 + l15;
    const float bias = PWb[oo] + NWb[oo];
    float s = 0.f, sq = 0.f;
    #pragma unroll
    for (int r = 0; r < 4; ++r) {
        const float yv = acc[r] + bias;
        y[(size_t)(bi0 + q4 * 4 + r) * O_ + oo] = yv;
        s += yv; sq += yv * yv;
    }
    s  += __shfl_xor(s, 16);  s  += __shfl_xor(s, 32);
    sq += __shfl_xor(sq, 16); sq += __shfl_xor(sq, 32);
    if (q4 == 0) {
        part[bid * 256 + oo]       = s;
        part[bid * 256 + 128 + oo] = sq;
    }
}

// ---------------------------------------------------------------------------
// bn_apply_fused (validated r17-r19): redundant stats reduce + BN + SELU.
// ---------------------------------------------------------------------------
__global__ __launch_bounds__(256) void bn_apply_fused(
    float* __restrict__ y, const float* __restrict__ part,
    const float* __restrict__ gamma, const float* __restrict__ beta)
{
    __shared__ float sStats[128];
    const int tid = threadIdx.x, o = tid & 63, g = tid >> 6;

    float s = 0.f, sq = 0.f;
    #pragma unroll 4
    for (int k = 0; k < 32; ++k) {
        const int blk = g * 32 + k;
        s  += part[blk * 256 + o];
        sq += part[blk * 256 + 128 + o];
    }
    __shared__ float ls[4][64], lq[4][64];
    ls[g][o] = s; lq[g][o] = sq;
    __syncthreads();
    if (tid < 64) {
        const float inv = 1.f / 2048.f;
        const float ts = ls[0][tid] + ls[1][tid] + ls[2][tid] + ls[3][tid];
        const float tq = lq[0][tid] + lq[1][tid] + lq[2][tid] + lq[3][tid];
        const float mu  = ts * inv;
        const float var = tq * inv - mu * mu;
        const float rstd = rsqrtf(var + 1e-5f);
        const float sc = gamma[tid] * rstd;
        sStats[tid]      = sc;
        sStats[64 + tid] = beta[tid] - mu * sc;
    }
    __syncthreads();

    const int idx = blockIdx.x * 256 + tid;
    f32x4 v = *(f32x4*)&y[idx * 4];
    const int o0 = (idx * 4) & 63;
    #pragma unroll
    for (int k = 0; k < 4; ++k) {
        const float t = v[k] * sStats[o0 + k] + sStats[64 + o0 + k];
        v[k] = t > 0.f ? SELU_SCALE * t : SELU_SCALE_ALPHA * (__expf(t) - 1.f);
    }
    *(f32x4*)&y[idx * 4] = v;
}

extern "C" void kernel_launch(void* const* d_in, const int* in_sizes, int n_in,
                              void* d_out, int out_size, void* d_ws, size_t ws_size,
                              hipStream_t stream)
{
    (void)in_sizes; (void)n_in; (void)out_size; (void)ws_size;
    const float* x     = (const float*)d_in[0];
    const float* Wa    = (const float*)d_in[1];
    const float* ba    = (const float*)d_in[2];
    const float* AW    = (const float*)d_in[3];
    const float* PW    = (const float*)d_in[4];
    const float* PWb   = (const float*)d_in[5];
    const float* NW    = (const float*)d_in[6];
    const float* NWb   = (const float*)d_in[7];
    const float* gamma = (const float*)d_in[8];
    const float* beta  = (const float*)d_in[9];

    char* ws = (char*)d_ws;
    ushort* xf    = (ushort*)ws;                                   // 1 MB
    ushort* xfT   = (ushort*)(ws + (1 << 20));                     // 1 MB
    ushort* X1h   = (ushort*)(ws + (2 << 20));                     // 2 MB
    ushort* X1l   = (ushort*)(ws + (4 << 20));                     // 2 MB
    ushort* pwf   = (ushort*)(ws + (6 << 20));                     // 128 KB
    ushort* nwf   = (ushort*)(ws + (6 << 20) + (128 << 10));       // 32 KB
    float*  part  = (float*)(ws + (6 << 20) + (160 << 10));        // 128 KB
    float*  y     = (float*)d_out;

    prep_frags<<<276, 256, 0, stream>>>(x, PW, NW, xf, xfT, pwf, nwf);
    attn_scores<<<dim3(N_, B_), 256, 0, stream>>>(x, xf, xfT, Wa, ba, AW, X1h, X1l);
    proj_y_part<<<128, 256, 0, stream>>>(X1h, X1l, xf, pwf, nwf, PWb, NWb, y, part);
    bn_apply_fused<<<128, 256, 0, stream>>>(y, part, gamma, beta);
}

// Round 21
// 91.994 us; speedup vs baseline: 1.2145x; 1.0428x over previous
//
#include <hip/hip_runtime.h>
#include <hip/hip_bf16.h>
#include <math.h>

#define B_ 4
#define N_ 512
#define D_ 128
#define O_ 64
#define H_ 4

#define SELU_SCALE 1.0507009873554805f
#define SELU_SCALE_ALPHA 1.7580993408473766f  // scale * alpha
#define LOG2E 1.4426950408889634f

typedef short  short8 __attribute__((ext_vector_type(8)));
typedef float  f32x4  __attribute__((ext_vector_type(4)));

__device__ __forceinline__ ushort bf16rne(float f) {
    uint u = __float_as_uint(f);
    return (ushort)((u + 0x7fffu + ((u >> 16) & 1u)) >> 16);
}
__device__ __forceinline__ void bf16split(float f, ushort& h, ushort& l) {
    h = bf16rne(f);
    float hf = __uint_as_float(((uint)h) << 16);
    l = bf16rne(f - hf);
}

// ---------------------------------------------------------------------------
// prep_frags (validated r3-r20): four fragment tensors by blockIdx range.
// ---------------------------------------------------------------------------
__global__ __launch_bounds__(256) void prep_frags(
    const float* __restrict__ x, const float* __restrict__ PW,
    const float* __restrict__ NW,
    ushort* __restrict__ xf, ushort* __restrict__ xfT,
    ushort* __restrict__ pwf, ushort* __restrict__ nwf)
{
    const int bid = blockIdx.x;
    const int tid = threadIdx.x;

    if (bid < 128) {
        const int t  = bid * 256 + tid;
        const int jg = t >> 4;
        const int dc = t & 15;
        const int jf = jg >> 4;
        const int kc = dc >> 2, q = dc & 3;
        const int lane = (jg & 15) | (q << 4);

        const f32x4 v0 = *(const f32x4*)&x[t * 8];
        const f32x4 v1 = *(const f32x4*)&x[t * 8 + 4];
        float vv[8] = {v0[0], v0[1], v0[2], v0[3], v1[0], v1[1], v1[2], v1[3]};
        short8 h8, l8;
        #pragma unroll
        for (int e = 0; e < 8; ++e) {
            ushort h, l; bf16split(vv[e], h, l);
            h8[e] = (short)h; l8[e] = (short)l;
        }
        const int fi = (jf * 4 + kc) * 2;
        *(short8*)&xf[(size_t)fi * 512 + lane * 8]       = h8;
        *(short8*)&xf[(size_t)(fi + 1) * 512 + lane * 8] = l8;
    } else if (bid < 256) {
        const int t    = (bid - 128) * 256 + tid;
        const int lane = t & 63, fr = t >> 6;
        const int d0 = fr & 7, kc = (fr >> 3) & 15, b = fr >> 7;
        const int l15 = lane & 15, q4 = lane >> 4;
        short8 h8, l8;
        #pragma unroll
        for (int e = 0; e < 8; ++e) {
            const float v = x[(size_t)((b * 512) + kc * 32 + q4 * 8 + e) * 128 + d0 * 16 + l15];
            ushort h, l; bf16split(v, h, l);
            h8[e] = (short)h; l8[e] = (short)l;
        }
        *(short8*)&xfT[(size_t)(fr * 2) * 512 + lane * 8]     = h8;
        *(short8*)&xfT[(size_t)(fr * 2 + 1) * 512 + lane * 8] = l8;
    } else if (bid < 272) {
        const int t    = (bid - 256) * 256 + tid;
        const int lane = t & 63, fr = t >> 6;
        const int o0 = fr & 3, kc = fr >> 2;
        const int l15 = lane & 15, q4 = lane >> 4;
        short8 h8, l8;
        #pragma unroll
        for (int e = 0; e < 8; ++e) {
            const int kk = kc * 32 + q4 * 8 + e;
            const int d = kk & 127, h = kk >> 7;
            const float v = PW[(d * 4 + h) * O_ + o0 * 16 + l15];
            ushort hh, ll; bf16split(v, hh, ll);
            h8[e] = (short)hh; l8[e] = (short)ll;
        }
        *(short8*)&pwf[(size_t)(fr * 2) * 512 + lane * 8]     = h8;
        *(short8*)&pwf[(size_t)(fr * 2 + 1) * 512 + lane * 8] = l8;
    } else {
        const int t    = (bid - 272) * 256 + tid;
        const int lane = t & 63, fr = t >> 6;
        const int o0 = fr & 3, kc = fr >> 2;
        const int l15 = lane & 15, q4 = lane >> 4;
        short8 h8, l8;
        #pragma unroll
        for (int e = 0; e < 8; ++e) {
            const float v = NW[(kc * 32 + q4 * 8 + e) * O_ + o0 * 16 + l15];
            ushort hh, ll; bf16split(v, hh, ll);
            h8[e] = (short)hh; l8[e] = (short)ll;
        }
        *(short8*)&nwf[(size_t)(fr * 2) * 512 + lane * 8]     = h8;
        *(short8*)&nwf[(size_t)(fr * 2 + 1) * 512 + lane * 8] = l8;
    }
}

#define SP_STRIDE 520

// compiler-proof 16B global load: UNIFORM SGPR base + per-lane VGPR byte
// offset + imm (r11 post-mortem: base must be wave-uniform for "s").
#define GLD(dst, off, base, IMM)                                     \
    asm volatile("global_load_dwordx4 %0, %1, %2 offset:" #IMM       \
                 : "=v"(dst) : "v"(off), "s"(base))

#define MFMA_BF16(A, Bv, C) __builtin_amdgcn_mfma_f32_16x16x32_bf16(A, Bv, C, 0, 0, 0)

// ---------------------------------------------------------------------------
// attn_scores: r20 structure (passed, 81 us). r21: (a) phase-3 drops x-LO
// (same validated byte-halving lever; P keeps hi/lo), loads 16->8/c-step,
// MFMA 24->16; (b) log2e folded into G2/b2 so epilogue uses exp2f (saves a
// v_mul per exp). Same (2,2) envelope, same GLD/counted-vmcnt pattern.
// ---------------------------------------------------------------------------
__global__ __launch_bounds__(256)
__attribute__((amdgpu_waves_per_eu(2, 2)))
void attn_scores(
    const float* __restrict__ x,
    const ushort* __restrict__ xf,
    const ushort* __restrict__ xfT,
    const float* __restrict__ Wa,
    const float* __restrict__ ba,
    const float* __restrict__ AW,
    ushort* __restrict__ X1h, ushort* __restrict__ X1l)
{
    __shared__ float sAmp[8 * SP_STRIDE];   // [wo*4+q4][j] logit partials; aliased as sXp
    __shared__ float sP[4 * SP_STRIDE];     // probs [h][j]

    const int tid  = threadIdx.x;
    const int i    = blockIdx.x;
    const int bB   = blockIdx.y;
    const int lane = tid & 63;
    const int w    = tid >> 6;
    const int l15  = lane & 15;
    const int q4   = lane >> 4;
    const int wo   = w >> 1;                // o-half
    const int wj   = w & 1;                 // j-half
    const f32x4 z = {0.f, 0.f, 0.f, 0.f};

    const ushort* xfb = xf + (size_t)(bB * 32) * 4096;     // block-uniform base
    const uint voff  = (uint)lane * 16u + (uint)wj * 131072u;
    const uint voff2 = voff + 4096u;

    // ---- prologue: issue this wave's tile-0 HI loads immediately ----
    short8 Bh0[4], Bh1[4];
    GLD(Bh0[0], voff,  xfb, 0);    GLD(Bh0[1], voff,  xfb, 2048);
    GLD(Bh0[2], voff2, xfb, 0);    GLD(Bh0[3], voff2, xfb, 2048);

    // ---- A-frags: two G2^T rows (2*log2e folded), o = wo*32+l15 / +16 ----
    const float* xi = x + ((size_t)bB * N_ + i) * D_;
    const int oa0 = wo * 32 + l15, oa1 = oa0 + 16;
    short8 gh0[4], gl0[4], gh1[4], gl1[4];
    #pragma unroll
    for (int kc = 0; kc < 4; ++kc) {
        const int d0 = kc * 32 + q4 * 8;
        const f32x4 a0 = *(const f32x4*)&xi[d0];
        const f32x4 a1 = *(const f32x4*)&xi[d0 + 4];
        #pragma unroll
        for (int e = 0; e < 8; ++e) {
            const float xe2 = (2.f * LOG2E) * ((e < 4) ? a0[e & 3] : a1[e & 3]);
            ushort h, l;
            bf16split(xe2 * Wa[(d0 + e) * O_ + oa0], h, l);
            gh0[kc][e] = (short)h; gl0[kc][e] = (short)l;
            bf16split(xe2 * Wa[(d0 + e) * O_ + oa1], h, l);
            gh1[kc][e] = (short)h; gl1[kc][e] = (short)l;
        }
    }

    // ---- epilogue constants: 8 o's per lane (4 per row) ----
    const int oc0 = wo * 32 + q4 * 4, oc1 = oc0 + 16;
    const f32x4 awA0 = *(const f32x4*)&AW[(oc0 + 0) * H_];
    const f32x4 awA1 = *(const f32x4*)&AW[(oc0 + 1) * H_];
    const f32x4 awA2 = *(const f32x4*)&AW[(oc0 + 2) * H_];
    const f32x4 awA3 = *(const f32x4*)&AW[(oc0 + 3) * H_];
    const f32x4 awB0 = *(const f32x4*)&AW[(oc1 + 0) * H_];
    const f32x4 awB1 = *(const f32x4*)&AW[(oc1 + 1) * H_];
    const f32x4 awB2 = *(const f32x4*)&AW[(oc1 + 2) * H_];
    const f32x4 awB3 = *(const f32x4*)&AW[(oc1 + 3) * H_];
    const f32x4 b2A = { (2.f * LOG2E) * ba[oc0], (2.f * LOG2E) * ba[oc0 + 1],
                        (2.f * LOG2E) * ba[oc0 + 2], (2.f * LOG2E) * ba[oc0 + 3] };
    const f32x4 b2B = { (2.f * LOG2E) * ba[oc1], (2.f * LOG2E) * ba[oc1 + 1],
                        (2.f * LOG2E) * ba[oc1 + 2], (2.f * LOG2E) * ba[oc1 + 3] };

// One tile T: issue next tile's 4 HI loads, counted wait, 16 MFMA in two
// chains, tanh via exp2 + am (dual chains), row store. No barriers.
#define SCORE_STEP(BHc, BHn, T)                                                     \
    {                                                                               \
        if ((T) < 15) {                                                             \
            const ushort* bp = xfb + (size_t)((T) + 1) * 4096;                      \
            GLD(BHn[0], voff,  bp, 0);    GLD(BHn[1], voff,  bp, 2048);             \
            GLD(BHn[2], voff2, bp, 0);    GLD(BHn[3], voff2, bp, 2048);             \
            asm volatile("s_waitcnt vmcnt(4)" ::: "memory");                        \
        } else {                                                                    \
            asm volatile("s_waitcnt vmcnt(0)" ::: "memory");                        \
        }                                                                           \
        __builtin_amdgcn_sched_barrier(0);                                          \
        f32x4 accA = b2A, accB = b2B;                                               \
        _Pragma("unroll")                                                           \
        for (int kc = 0; kc < 4; ++kc) {                                            \
            accA = MFMA_BF16(gh0[kc], BHc[kc], accA);                               \
            accB = MFMA_BF16(gh1[kc], BHc[kc], accB);                               \
            accA = MFMA_BF16(gl0[kc], BHc[kc], accA);                               \
            accB = MFMA_BF16(gl1[kc], BHc[kc], accB);                               \
        }                                                                           \
        f32x4 amA, amB;                                                             \
        {                                                                           \
            const float e0 = exp2f(accA[0]);                                        \
            const float e1 = exp2f(accA[1]);                                        \
            const float e2 = exp2f(accA[2]);                                        \
            const float e3 = exp2f(accA[3]);                                        \
            const float f0 = exp2f(accB[0]);                                        \
            const float f1 = exp2f(accB[1]);                                        \
            const float f2 = exp2f(accB[2]);                                        \
            const float f3 = exp2f(accB[3]);                                        \
            amA  = fmaf(-2.f, __builtin_amdgcn_rcpf(e0 + 1.f), 1.f) * awA0;         \
            amB  = fmaf(-2.f, __builtin_amdgcn_rcpf(f0 + 1.f), 1.f) * awB0;         \
            amA += fmaf(-2.f, __builtin_amdgcn_rcpf(e1 + 1.f), 1.f) * awA1;         \
            amB += fmaf(-2.f, __builtin_amdgcn_rcpf(f1 + 1.f), 1.f) * awB1;         \
            amA += fmaf(-2.f, __builtin_amdgcn_rcpf(e2 + 1.f), 1.f) * awA2;         \
            amB += fmaf(-2.f, __builtin_amdgcn_rcpf(f2 + 1.f), 1.f) * awB2;         \
            amA += fmaf(-2.f, __builtin_amdgcn_rcpf(e3 + 1.f), 1.f) * awA3;         \
            amB += fmaf(-2.f, __builtin_amdgcn_rcpf(f3 + 1.f), 1.f) * awB3;         \
        }                                                                           \
        f32x4 am = amA + amB;                                                       \
        _Pragma("unroll")                                                           \
        for (int k = 0; k < 4; ++k) {                                               \
            am[k] += __shfl_xor(am[k], 16);                                         \
            am[k] += __shfl_xor(am[k], 32);                                         \
        }                                                                           \
        const float amsel = (q4 == 0) ? am[0] : (q4 == 1) ? am[1]                   \
                          : (q4 == 2) ? am[2] : am[3];                              \
        sAmp[(wo * 4 + q4) * SP_STRIDE + (wj * 16 + (T)) * 16 + l15] = amsel;       \
    }

    for (int t = 0; t < 7; ++t) {
        SCORE_STEP(Bh0, Bh1, 2 * t)
        SCORE_STEP(Bh1, Bh0, 2 * t + 1)
    }
    SCORE_STEP(Bh0, Bh1, 14)
    SCORE_STEP(Bh1, Bh0, 15)
#undef SCORE_STEP
    __syncthreads();   // all logit rows visible

    // ---- phase-3 prefetch setup; c=0 HI loads issued NOW, hidden by softmax
    short8 XA[8], XB[8];
    uint offs[8];
    #pragma unroll
    for (int nf = 0; nf < 8; ++nf)
        offs[nf] = (uint)lane * 16u + (uint)w * 65536u + (uint)nf * 2048u;
    {
        const ushort* bp3 = xfT + (size_t)(bB * 16) * 8192;   // c = 0 base
        #pragma unroll
        for (int nf = 0; nf < 8; ++nf) GLD(XA[nf], offs[nf], bp3, 0);
    }

    // ---- phase 2: softmax over j, one wave per head; 2-way combine ----
    {
        const int h = w;
        float v[8];
        float m = -INFINITY;
        #pragma unroll
        for (int k = 0; k < 8; ++k) {
            const int j = k * 64 + lane;
            v[k] = sAmp[h * SP_STRIDE + j] + sAmp[(4 + h) * SP_STRIDE + j];
            m = fmaxf(m, v[k]);
        }
        #pragma unroll
        for (int s = 32; s >= 1; s >>= 1) m = fmaxf(m, __shfl_xor(m, s));
        float l = 0.f;
        #pragma unroll
        for (int k = 0; k < 8; ++k) { v[k] = __expf(v[k] - m); l += v[k]; }
        #pragma unroll
        for (int s = 32; s >= 1; s >>= 1) l += __shfl_xor(l, s);
        const float rinv = 1.f / l;
        #pragma unroll
        for (int k = 0; k < 8; ++k) sP[h * SP_STRIDE + k * 64 + lane] = v[k] * rinv;
    }
    __syncthreads();

    // ---- phase 3: x1 = P.Xhi via MFMA, GLD-pipelined at c granularity ----
    f32x4 acc2[8];
    #pragma unroll
    for (int nf = 0; nf < 8; ++nf) acc2[nf] = z;

#define P3_STEP(XC, XN, C)                                                          \
    {                                                                               \
        if ((C) < 3) {                                                              \
            const ushort* bp3 = xfT + (size_t)(bB * 16 + (C) + 1) * 8192;           \
            _Pragma("unroll")                                                       \
            for (int nf = 0; nf < 8; ++nf) GLD(XN[nf], offs[nf], bp3, 0);           \
        }                                                                           \
        const int kc = w * 4 + (C);                                                 \
        const int base = (l15 & 3) * SP_STRIDE + kc * 32 + q4 * 8;                  \
        const f32x4 p0 = *(const f32x4*)&sP[base];                                  \
        const f32x4 p1 = *(const f32x4*)&sP[base + 4];                              \
        float pv[8] = {p0[0], p0[1], p0[2], p0[3], p1[0], p1[1], p1[2], p1[3]};     \
        short8 pah, pal;                                                            \
        _Pragma("unroll")                                                           \
        for (int e = 0; e < 8; ++e) {                                               \
            ushort h, l; bf16split(pv[e], h, l);                                    \
            pah[e] = (short)h; pal[e] = (short)l;                                   \
        }                                                                           \
        if ((C) < 3) { asm volatile("s_waitcnt vmcnt(8)" ::: "memory"); }           \
        else         { asm volatile("s_waitcnt vmcnt(0)" ::: "memory"); }           \
        __builtin_amdgcn_sched_barrier(0);                                          \
        _Pragma("unroll")                                                           \
        for (int nf = 0; nf < 8; ++nf) {                                            \
            acc2[nf] = MFMA_BF16(pah, XC[nf], acc2[nf]);                            \
            acc2[nf] = MFMA_BF16(pal, XC[nf], acc2[nf]);                            \
        }                                                                           \
    }

    P3_STEP(XA, XB, 0)
    P3_STEP(XB, XA, 1)
    P3_STEP(XA, XB, 2)
    P3_STEP(XB, XA, 3)
#undef P3_STEP

    float* sXp = sAmp;   // reuse logit rows as [16][128] wave partials
    if (q4 == 0) {
        #pragma unroll
        for (int nf = 0; nf < 8; ++nf)
            #pragma unroll
            for (int r = 0; r < 4; ++r)
                sXp[(w * 4 + r) * 128 + nf * 16 + l15] = acc2[nf][r];
    }
    __syncthreads();

    // ---- phase 3b: reduce wave partials, split, store X1 ----
    {
        const int kap = tid * 2;
        const size_t row = (size_t)bB * N_ + i;
        float v0 = 0.f, v1 = 0.f;
        #pragma unroll
        for (int ww = 0; ww < 4; ++ww) {
            v0 += sXp[(ww * 4 + (kap >> 7)) * 128 + (kap & 127)];
            v1 += sXp[(ww * 4 + ((kap + 1) >> 7)) * 128 + ((kap + 1) & 127)];
        }
        ushort h0, l0, h1, l1;
        bf16split(v0, h0, l0);
        bf16split(v1, h1, l1);
        *(uint*)&X1h[row * 512 + kap] = (uint)h0 | ((uint)h1 << 16);
        *(uint*)&X1l[row * 512 + kap] = (uint)l0 | ((uint)l1 << 16);
    }
}

// ---------------------------------------------------------------------------
// proj_y_part: y = x1.PW' + x.NW + biases (MFMA) + per-block BN partial sums.
// ---------------------------------------------------------------------------
__global__ __launch_bounds__(256) void proj_y_part(
    const ushort* __restrict__ X1h, const ushort* __restrict__ X1l,
    const ushort* __restrict__ xf,
    const ushort* __restrict__ pwf, const ushort* __restrict__ nwf,
    const float* __restrict__ PWb, const float* __restrict__ NWb,
    float* __restrict__ y, float* __restrict__ part)
{
    const int tid = threadIdx.x, bid = blockIdx.x;
    const int lane = tid & 63, w = tid >> 6;
    const int l15 = lane & 15, q4 = lane >> 4;
    const int bi0 = bid * 16;
    const int b = bi0 >> 9, ig = (bi0 >> 4) & 31;

    f32x4 acc = {0.f, 0.f, 0.f, 0.f};
    #pragma unroll
    for (int kc = 0; kc < 16; ++kc) {
        const size_t arow = (size_t)(bi0 + l15) * 512 + kc * 32 + q4 * 8;
        const short8 ah = *(const short8*)&X1h[arow];
        const short8 al = *(const short8*)&X1l[arow];
        const int f3 = (kc * 4 + w) * 2;
        const short8 bhv = *(const short8*)&pwf[(size_t)f3 * 512 + lane * 8];
        const short8 blv = *(const short8*)&pwf[(size_t)(f3 + 1) * 512 + lane * 8];
        acc = MFMA_BF16(ah, bhv, acc);
        acc = MFMA_BF16(al, bhv, acc);
        acc = MFMA_BF16(ah, blv, acc);
    }
    #pragma unroll
    for (int kc = 0; kc < 4; ++kc) {
        const size_t fi = ((size_t)(b * 32 + ig) * 4 + kc) * 2;
        const short8 ah = *(const short8*)&xf[fi * 512 + lane * 8];
        const short8 al = *(const short8*)&xf[(fi + 1) * 512 + lane * 8];
        const int f4 = (kc * 4 + w) * 2;
        const short8 bhv = *(const short8*)&nwf[(size_t)f4 * 512 + lane * 8];
        const short8 blv = *(const short8*)&nwf[(size_t)(f4 + 1) * 512 + lane * 8];
        acc = MFMA_BF16(ah, bhv, acc);
        acc = MFMA_BF16(al, bhv, acc);
        acc = MFMA_BF16(ah, blv, acc);
    }
    const int oo = w * 16 + l15;
    const float bias = PWb[oo] + NWb[oo];
    float s = 0.f, sq = 0.f;
    #pragma unroll
    for (int r = 0; r < 4; ++r) {
        const float yv = acc[r] + bias;
        y[(size_t)(bi0 + q4 * 4 + r) * O_ + oo] = yv;
        s += yv; sq += yv * yv;
    }
    s  += __shfl_xor(s, 16);  s  += __shfl_xor(s, 32);
    sq += __shfl_xor(sq, 16); sq += __shfl_xor(sq, 32);
    if (q4 == 0) {
        part[bid * 256 + oo]       = s;
        part[bid * 256 + 128 + oo] = sq;
    }
}

// ---------------------------------------------------------------------------
// bn_apply_fused (validated r17-r20): redundant stats reduce + BN + SELU.
// ---------------------------------------------------------------------------
__global__ __launch_bounds__(256) void bn_apply_fused(
    float* __restrict__ y, const float* __restrict__ part,
    const float* __restrict__ gamma, const float* __restrict__ beta)
{
    __shared__ float sStats[128];
    const int tid = threadIdx.x, o = tid & 63, g = tid >> 6;

    float s = 0.f, sq = 0.f;
    #pragma unroll 4
    for (int k = 0; k < 32; ++k) {
        const int blk = g * 32 + k;
        s  += part[blk * 256 + o];
        sq += part[blk * 256 + 128 + o];
    }
    __shared__ float ls[4][64], lq[4][64];
    ls[g][o] = s; lq[g][o] = sq;
    __syncthreads();
    if (tid < 64) {
        const float inv = 1.f / 2048.f;
        const float ts = ls[0][tid] + ls[1][tid] + ls[2][tid] + ls[3][tid];
        const float tq = lq[0][tid] + lq[1][tid] + lq[2][tid] + lq[3][tid];
        const float mu  = ts * inv;
        const float var = tq * inv - mu * mu;
        const float rstd = rsqrtf(var + 1e-5f);
        const float sc = gamma[tid] * rstd;
        sStats[tid]      = sc;
        sStats[64 + tid] = beta[tid] - mu * sc;
    }
    __syncthreads();

    const int idx = blockIdx.x * 256 + tid;
    f32x4 v = *(f32x4*)&y[idx * 4];
    const int o0 = (idx * 4) & 63;
    #pragma unroll
    for (int k = 0; k < 4; ++k) {
        const float t = v[k] * sStats[o0 + k] + sStats[64 + o0 + k];
        v[k] = t > 0.f ? SELU_SCALE * t : SELU_SCALE_ALPHA * (__expf(t) - 1.f);
    }
    *(f32x4*)&y[idx * 4] = v;
}

extern "C" void kernel_launch(void* const* d_in, const int* in_sizes, int n_in,
                              void* d_out, int out_size, void* d_ws, size_t ws_size,
                              hipStream_t stream)
{
    (void)in_sizes; (void)n_in; (void)out_size; (void)ws_size;
    const float* x     = (const float*)d_in[0];
    const float* Wa    = (const float*)d_in[1];
    const float* ba    = (const float*)d_in[2];
    const float* AW    = (const float*)d_in[3];
    const float* PW    = (const float*)d_in[4];
    const float* PWb   = (const float*)d_in[5];
    const float* NW    = (const float*)d_in[6];
    const float* NWb   = (const float*)d_in[7];
    const float* gamma = (const float*)d_in[8];
    const float* beta  = (const float*)d_in[9];

    char* ws = (char*)d_ws;
    ushort* xf    = (ushort*)ws;                                   // 1 MB
    ushort* xfT   = (ushort*)(ws + (1 << 20));                     // 1 MB
    ushort* X1h   = (ushort*)(ws + (2 << 20));                     // 2 MB
    ushort* X1l   = (ushort*)(ws + (4 << 20));                     // 2 MB
    ushort* pwf   = (ushort*)(ws + (6 << 20));                     // 128 KB
    ushort* nwf   = (ushort*)(ws + (6 << 20) + (128 << 10));       // 32 KB
    float*  part  = (float*)(ws + (6 << 20) + (160 << 10));        // 128 KB
    float*  y     = (float*)d_out;

    prep_frags<<<276, 256, 0, stream>>>(x, PW, NW, xf, xfT, pwf, nwf);
    attn_scores<<<dim3(N_, B_), 256, 0, stream>>>(x, xf, xfT, Wa, ba, AW, X1h, X1l);
    proj_y_part<<<128, 256, 0, stream>>>(X1h, X1l, xf, pwf, nwf, PWb, NWb, y, part);
    bn_apply_fused<<<128, 256, 0, stream>>>(y, part, gamma, beta);
}

// Round 22
// 78.868 us; speedup vs baseline: 1.4167x; 1.1664x over previous
//
#include <hip/hip_runtime.h>
#include <hip/hip_bf16.h>
#include <math.h>

#define B_ 4
#define N_ 512
#define D_ 128
#define O_ 64
#define H_ 4

#define SELU_SCALE 1.0507009873554805f
#define SELU_SCALE_ALPHA 1.7580993408473766f  // scale * alpha
#define LOG2E 1.4426950408889634f

typedef short  short8 __attribute__((ext_vector_type(8)));
typedef float  f32x4  __attribute__((ext_vector_type(4)));

__device__ __forceinline__ ushort bf16rne(float f) {
    uint u = __float_as_uint(f);
    return (ushort)((u + 0x7fffu + ((u >> 16) & 1u)) >> 16);
}
__device__ __forceinline__ void bf16split(float f, ushort& h, ushort& l) {
    h = bf16rne(f);
    float hf = __uint_as_float(((uint)h) << 16);
    l = bf16rne(f - hf);
}

// ---------------------------------------------------------------------------
// prep_frags (validated r3-r21): four fragment tensors by blockIdx range.
// ---------------------------------------------------------------------------
__global__ __launch_bounds__(256) void prep_frags(
    const float* __restrict__ x, const float* __restrict__ PW,
    const float* __restrict__ NW,
    ushort* __restrict__ xf, ushort* __restrict__ xfT,
    ushort* __restrict__ pwf, ushort* __restrict__ nwf)
{
    const int bid = blockIdx.x;
    const int tid = threadIdx.x;

    if (bid < 128) {
        const int t  = bid * 256 + tid;
        const int jg = t >> 4;
        const int dc = t & 15;
        const int jf = jg >> 4;
        const int kc = dc >> 2, q = dc & 3;
        const int lane = (jg & 15) | (q << 4);

        const f32x4 v0 = *(const f32x4*)&x[t * 8];
        const f32x4 v1 = *(const f32x4*)&x[t * 8 + 4];
        float vv[8] = {v0[0], v0[1], v0[2], v0[3], v1[0], v1[1], v1[2], v1[3]};
        short8 h8, l8;
        #pragma unroll
        for (int e = 0; e < 8; ++e) {
            ushort h, l; bf16split(vv[e], h, l);
            h8[e] = (short)h; l8[e] = (short)l;
        }
        const int fi = (jf * 4 + kc) * 2;
        *(short8*)&xf[(size_t)fi * 512 + lane * 8]       = h8;
        *(short8*)&xf[(size_t)(fi + 1) * 512 + lane * 8] = l8;
    } else if (bid < 256) {
        const int t    = (bid - 128) * 256 + tid;
        const int lane = t & 63, fr = t >> 6;
        const int d0 = fr & 7, kc = (fr >> 3) & 15, b = fr >> 7;
        const int l15 = lane & 15, q4 = lane >> 4;
        short8 h8, l8;
        #pragma unroll
        for (int e = 0; e < 8; ++e) {
            const float v = x[(size_t)((b * 512) + kc * 32 + q4 * 8 + e) * 128 + d0 * 16 + l15];
            ushort h, l; bf16split(v, h, l);
            h8[e] = (short)h; l8[e] = (short)l;
        }
        *(short8*)&xfT[(size_t)(fr * 2) * 512 + lane * 8]     = h8;
        *(short8*)&xfT[(size_t)(fr * 2 + 1) * 512 + lane * 8] = l8;
    } else if (bid < 272) {
        const int t    = (bid - 256) * 256 + tid;
        const int lane = t & 63, fr = t >> 6;
        const int o0 = fr & 3, kc = fr >> 2;
        const int l15 = lane & 15, q4 = lane >> 4;
        short8 h8, l8;
        #pragma unroll
        for (int e = 0; e < 8; ++e) {
            const int kk = kc * 32 + q4 * 8 + e;
            const int d = kk & 127, h = kk >> 7;
            const float v = PW[(d * 4 + h) * O_ + o0 * 16 + l15];
            ushort hh, ll; bf16split(v, hh, ll);
            h8[e] = (short)hh; l8[e] = (short)ll;
        }
        *(short8*)&pwf[(size_t)(fr * 2) * 512 + lane * 8]     = h8;
        *(short8*)&pwf[(size_t)(fr * 2 + 1) * 512 + lane * 8] = l8;
    } else {
        const int t    = (bid - 272) * 256 + tid;
        const int lane = t & 63, fr = t >> 6;
        const int o0 = fr & 3, kc = fr >> 2;
        const int l15 = lane & 15, q4 = lane >> 4;
        short8 h8, l8;
        #pragma unroll
        for (int e = 0; e < 8; ++e) {
            const float v = NW[(kc * 32 + q4 * 8 + e) * O_ + o0 * 16 + l15];
            ushort hh, ll; bf16split(v, hh, ll);
            h8[e] = (short)hh; l8[e] = (short)ll;
        }
        *(short8*)&nwf[(size_t)(fr * 2) * 512 + lane * 8]     = h8;
        *(short8*)&nwf[(size_t)(fr * 2 + 1) * 512 + lane * 8] = l8;
    }
}

#define SP_STRIDE 520

// compiler-proof 16B global load: UNIFORM SGPR base + per-lane VGPR byte
// offset + imm (r11 post-mortem: base must be wave-uniform for "s").
#define GLD(dst, off, base, IMM)                                     \
    asm volatile("global_load_dwordx4 %0, %1, %2 offset:" #IMM       \
                 : "=v"(dst) : "v"(off), "s"(base))

#define MFMA_BF16(A, Bv, C) __builtin_amdgcn_mfma_f32_16x16x32_bf16(A, Bv, C, 0, 0, 0)

// ---------------------------------------------------------------------------
// attn_scores: r21 structure (passed, 77.5 us). r22: (a) drop G-LO in phase 1
// (scores = Gh*xh; r20/r21 proved this error class contributes ZERO absmax) ->
// MFMA 16->8/tile, A-frags halve; (b) drop P-LO in phase 3 -> MFMA 16->8/
// c-step, splits -> single bf16rne. X1 keeps hi/lo. Same (2,2) envelope,
// same GLD/counted-vmcnt pattern (counts unchanged: 4-load tiles / 8-load
// c-steps).
// ---------------------------------------------------------------------------
__global__ __launch_bounds__(256)
__attribute__((amdgpu_waves_per_eu(2, 2)))
void attn_scores(
    const float* __restrict__ x,
    const ushort* __restrict__ xf,
    const ushort* __restrict__ xfT,
    const float* __restrict__ Wa,
    const float* __restrict__ ba,
    const float* __restrict__ AW,
    ushort* __restrict__ X1h, ushort* __restrict__ X1l)
{
    __shared__ float sAmp[8 * SP_STRIDE];   // [wo*4+q4][j] logit partials; aliased as sXp
    __shared__ float sP[4 * SP_STRIDE];     // probs [h][j]

    const int tid  = threadIdx.x;
    const int i    = blockIdx.x;
    const int bB   = blockIdx.y;
    const int lane = tid & 63;
    const int w    = tid >> 6;
    const int l15  = lane & 15;
    const int q4   = lane >> 4;
    const int wo   = w >> 1;                // o-half
    const int wj   = w & 1;                 // j-half
    const f32x4 z = {0.f, 0.f, 0.f, 0.f};

    const ushort* xfb = xf + (size_t)(bB * 32) * 4096;     // block-uniform base
    const uint voff  = (uint)lane * 16u + (uint)wj * 131072u;
    const uint voff2 = voff + 4096u;

    // ---- prologue: issue this wave's tile-0 HI loads immediately ----
    short8 Bh0[4], Bh1[4];
    GLD(Bh0[0], voff,  xfb, 0);    GLD(Bh0[1], voff,  xfb, 2048);
    GLD(Bh0[2], voff2, xfb, 0);    GLD(Bh0[3], voff2, xfb, 2048);

    // ---- A-frags: two G2^T HI rows (2*log2e folded), o = wo*32+l15 / +16 ----
    const float* xi = x + ((size_t)bB * N_ + i) * D_;
    const int oa0 = wo * 32 + l15, oa1 = oa0 + 16;
    short8 gh0[4], gh1[4];
    #pragma unroll
    for (int kc = 0; kc < 4; ++kc) {
        const int d0 = kc * 32 + q4 * 8;
        const f32x4 a0 = *(const f32x4*)&xi[d0];
        const f32x4 a1 = *(const f32x4*)&xi[d0 + 4];
        #pragma unroll
        for (int e = 0; e < 8; ++e) {
            const float xe2 = (2.f * LOG2E) * ((e < 4) ? a0[e & 3] : a1[e & 3]);
            gh0[kc][e] = (short)bf16rne(xe2 * Wa[(d0 + e) * O_ + oa0]);
            gh1[kc][e] = (short)bf16rne(xe2 * Wa[(d0 + e) * O_ + oa1]);
        }
    }

    // ---- epilogue constants: 8 o's per lane (4 per row) ----
    const int oc0 = wo * 32 + q4 * 4, oc1 = oc0 + 16;
    const f32x4 awA0 = *(const f32x4*)&AW[(oc0 + 0) * H_];
    const f32x4 awA1 = *(const f32x4*)&AW[(oc0 + 1) * H_];
    const f32x4 awA2 = *(const f32x4*)&AW[(oc0 + 2) * H_];
    const f32x4 awA3 = *(const f32x4*)&AW[(oc0 + 3) * H_];
    const f32x4 awB0 = *(const f32x4*)&AW[(oc1 + 0) * H_];
    const f32x4 awB1 = *(const f32x4*)&AW[(oc1 + 1) * H_];
    const f32x4 awB2 = *(const f32x4*)&AW[(oc1 + 2) * H_];
    const f32x4 awB3 = *(const f32x4*)&AW[(oc1 + 3) * H_];
    const f32x4 b2A = { (2.f * LOG2E) * ba[oc0], (2.f * LOG2E) * ba[oc0 + 1],
                        (2.f * LOG2E) * ba[oc0 + 2], (2.f * LOG2E) * ba[oc0 + 3] };
    const f32x4 b2B = { (2.f * LOG2E) * ba[oc1], (2.f * LOG2E) * ba[oc1 + 1],
                        (2.f * LOG2E) * ba[oc1 + 2], (2.f * LOG2E) * ba[oc1 + 3] };

// One tile T: issue next tile's 4 HI loads, counted wait, 8 MFMA in two
// chains, tanh via exp2 + am (dual chains), row store. No barriers.
#define SCORE_STEP(BHc, BHn, T)                                                     \
    {                                                                               \
        if ((T) < 15) {                                                             \
            const ushort* bp = xfb + (size_t)((T) + 1) * 4096;                      \
            GLD(BHn[0], voff,  bp, 0);    GLD(BHn[1], voff,  bp, 2048);             \
            GLD(BHn[2], voff2, bp, 0);    GLD(BHn[3], voff2, bp, 2048);             \
            asm volatile("s_waitcnt vmcnt(4)" ::: "memory");                        \
        } else {                                                                    \
            asm volatile("s_waitcnt vmcnt(0)" ::: "memory");                        \
        }                                                                           \
        __builtin_amdgcn_sched_barrier(0);                                          \
        f32x4 accA = b2A, accB = b2B;                                               \
        _Pragma("unroll")                                                           \
        for (int kc = 0; kc < 4; ++kc) {                                            \
            accA = MFMA_BF16(gh0[kc], BHc[kc], accA);                               \
            accB = MFMA_BF16(gh1[kc], BHc[kc], accB);                               \
        }                                                                           \
        f32x4 amA, amB;                                                             \
        {                                                                           \
            const float e0 = exp2f(accA[0]);                                        \
            const float e1 = exp2f(accA[1]);                                        \
            const float e2 = exp2f(accA[2]);                                        \
            const float e3 = exp2f(accA[3]);                                        \
            const float f0 = exp2f(accB[0]);                                        \
            const float f1 = exp2f(accB[1]);                                        \
            const float f2 = exp2f(accB[2]);                                        \
            const float f3 = exp2f(accB[3]);                                        \
            amA  = fmaf(-2.f, __builtin_amdgcn_rcpf(e0 + 1.f), 1.f) * awA0;         \
            amB  = fmaf(-2.f, __builtin_amdgcn_rcpf(f0 + 1.f), 1.f) * awB0;         \
            amA += fmaf(-2.f, __builtin_amdgcn_rcpf(e1 + 1.f), 1.f) * awA1;         \
            amB += fmaf(-2.f, __builtin_amdgcn_rcpf(f1 + 1.f), 1.f) * awB1;         \
            amA += fmaf(-2.f, __builtin_amdgcn_rcpf(e2 + 1.f), 1.f) * awA2;         \
            amB += fmaf(-2.f, __builtin_amdgcn_rcpf(f2 + 1.f), 1.f) * awB2;         \
            amA += fmaf(-2.f, __builtin_amdgcn_rcpf(e3 + 1.f), 1.f) * awA3;         \
            amB += fmaf(-2.f, __builtin_amdgcn_rcpf(f3 + 1.f), 1.f) * awB3;         \
        }                                                                           \
        f32x4 am = amA + amB;                                                       \
        _Pragma("unroll")                                                           \
        for (int k = 0; k < 4; ++k) {                                               \
            am[k] += __shfl_xor(am[k], 16);                                         \
            am[k] += __shfl_xor(am[k], 32);                                         \
        }                                                                           \
        const float amsel = (q4 == 0) ? am[0] : (q4 == 1) ? am[1]                   \
                          : (q4 == 2) ? am[2] : am[3];                              \
        sAmp[(wo * 4 + q4) * SP_STRIDE + (wj * 16 + (T)) * 16 + l15] = amsel;       \
    }

    for (int t = 0; t < 7; ++t) {
        SCORE_STEP(Bh0, Bh1, 2 * t)
        SCORE_STEP(Bh1, Bh0, 2 * t + 1)
    }
    SCORE_STEP(Bh0, Bh1, 14)
    SCORE_STEP(Bh1, Bh0, 15)
#undef SCORE_STEP
    __syncthreads();   // all logit rows visible

    // ---- phase-3 prefetch setup; c=0 HI loads issued NOW, hidden by softmax
    short8 XA[8], XB[8];
    uint offs[8];
    #pragma unroll
    for (int nf = 0; nf < 8; ++nf)
        offs[nf] = (uint)lane * 16u + (uint)w * 65536u + (uint)nf * 2048u;
    {
        const ushort* bp3 = xfT + (size_t)(bB * 16) * 8192;   // c = 0 base
        #pragma unroll
        for (int nf = 0; nf < 8; ++nf) GLD(XA[nf], offs[nf], bp3, 0);
    }

    // ---- phase 2: softmax over j, one wave per head; 2-way combine ----
    {
        const int h = w;
        float v[8];
        float m = -INFINITY;
        #pragma unroll
        for (int k = 0; k < 8; ++k) {
            const int j = k * 64 + lane;
            v[k] = sAmp[h * SP_STRIDE + j] + sAmp[(4 + h) * SP_STRIDE + j];
            m = fmaxf(m, v[k]);
        }
        #pragma unroll
        for (int s = 32; s >= 1; s >>= 1) m = fmaxf(m, __shfl_xor(m, s));
        float l = 0.f;
        #pragma unroll
        for (int k = 0; k < 8; ++k) { v[k] = __expf(v[k] - m); l += v[k]; }
        #pragma unroll
        for (int s = 32; s >= 1; s >>= 1) l += __shfl_xor(l, s);
        const float rinv = 1.f / l;
        #pragma unroll
        for (int k = 0; k < 8; ++k) sP[h * SP_STRIDE + k * 64 + lane] = v[k] * rinv;
    }
    __syncthreads();

    // ---- phase 3: x1 = Phi.Xhi via MFMA, GLD-pipelined at c granularity ----
    f32x4 acc2[8];
    #pragma unroll
    for (int nf = 0; nf < 8; ++nf) acc2[nf] = z;

#define P3_STEP(XC, XN, C)                                                          \
    {                                                                               \
        if ((C) < 3) {                                                              \
            const ushort* bp3 = xfT + (size_t)(bB * 16 + (C) + 1) * 8192;           \
            _Pragma("unroll")                                                       \
            for (int nf = 0; nf < 8; ++nf) GLD(XN[nf], offs[nf], bp3, 0);           \
        }                                                                           \
        const int kc = w * 4 + (C);                                                 \
        const int base = (l15 & 3) * SP_STRIDE + kc * 32 + q4 * 8;                  \
        const f32x4 p0 = *(const f32x4*)&sP[base];                                  \
        const f32x4 p1 = *(const f32x4*)&sP[base + 4];                              \
        float pv[8] = {p0[0], p0[1], p0[2], p0[3], p1[0], p1[1], p1[2], p1[3]};     \
        short8 pah;                                                                 \
        _Pragma("unroll")                                                           \
        for (int e = 0; e < 8; ++e) pah[e] = (short)bf16rne(pv[e]);                 \
        if ((C) < 3) { asm volatile("s_waitcnt vmcnt(8)" ::: "memory"); }           \
        else         { asm volatile("s_waitcnt vmcnt(0)" ::: "memory"); }           \
        __builtin_amdgcn_sched_barrier(0);                                          \
        _Pragma("unroll")                                                           \
        for (int nf = 0; nf < 8; ++nf)                                              \
            acc2[nf] = MFMA_BF16(pah, XC[nf], acc2[nf]);                            \
    }

    P3_STEP(XA, XB, 0)
    P3_STEP(XB, XA, 1)
    P3_STEP(XA, XB, 2)
    P3_STEP(XB, XA, 3)
#undef P3_STEP

    float* sXp = sAmp;   // reuse logit rows as [16][128] wave partials
    if (q4 == 0) {
        #pragma unroll
        for (int nf = 0; nf < 8; ++nf)
            #pragma unroll
            for (int r = 0; r < 4; ++r)
                sXp[(w * 4 + r) * 128 + nf * 16 + l15] = acc2[nf][r];
    }
    __syncthreads();

    // ---- phase 3b: reduce wave partials, split, store X1 ----
    {
        const int kap = tid * 2;
        const size_t row = (size_t)bB * N_ + i;
        float v0 = 0.f, v1 = 0.f;
        #pragma unroll
        for (int ww = 0; ww < 4; ++ww) {
            v0 += sXp[(ww * 4 + (kap >> 7)) * 128 + (kap & 127)];
            v1 += sXp[(ww * 4 + ((kap + 1) >> 7)) * 128 + ((kap + 1) & 127)];
        }
        ushort h0, l0, h1, l1;
        bf16split(v0, h0, l0);
        bf16split(v1, h1, l1);
        *(uint*)&X1h[row * 512 + kap] = (uint)h0 | ((uint)h1 << 16);
        *(uint*)&X1l[row * 512 + kap] = (uint)l0 | ((uint)l1 << 16);
    }
}

// ---------------------------------------------------------------------------
// proj_y_part: y = x1.PW' + x.NW + biases (MFMA) + per-block BN partial sums.
// ---------------------------------------------------------------------------
__global__ __launch_bounds__(256) void proj_y_part(
    const ushort* __restrict__ X1h, const ushort* __restrict__ X1l,
    const ushort* __restrict__ xf,
    const ushort* __restrict__ pwf, const ushort* __restrict__ nwf,
    const float* __restrict__ PWb, const float* __restrict__ NWb,
    float* __restrict__ y, float* __restrict__ part)
{
    const int tid = threadIdx.x, bid = blockIdx.x;
    const int lane = tid & 63, w = tid >> 6;
    const int l15 = lane & 15, q4 = lane >> 4;
    const int bi0 = bid * 16;
    const int b = bi0 >> 9, ig = (bi0 >> 4) & 31;

    f32x4 acc = {0.f, 0.f, 0.f, 0.f};
    #pragma unroll
    for (int kc = 0; kc < 16; ++kc) {
        const size_t arow = (size_t)(bi0 + l15) * 512 + kc * 32 + q4 * 8;
        const short8 ah = *(const short8*)&X1h[arow];
        const short8 al = *(const short8*)&X1l[arow];
        const int f3 = (kc * 4 + w) * 2;
        const short8 bhv = *(const short8*)&pwf[(size_t)f3 * 512 + lane * 8];
        const short8 blv = *(const short8*)&pwf[(size_t)(f3 + 1) * 512 + lane * 8];
        acc = MFMA_BF16(ah, bhv, acc);
        acc = MFMA_BF16(al, bhv, acc);
        acc = MFMA_BF16(ah, blv, acc);
    }
    #pragma unroll
    for (int kc = 0; kc < 4; ++kc) {
        const size_t fi = ((size_t)(b * 32 + ig) * 4 + kc) * 2;
        const short8 ah = *(const short8*)&xf[fi * 512 + lane * 8];
        const short8 al = *(const short8*)&xf[(fi + 1) * 512 + lane * 8];
        const int f4 = (kc * 4 + w) * 2;
        const short8 bhv = *(const short8*)&nwf[(size_t)f4 * 512 + lane * 8];
        const short8 blv = *(const short8*)&nwf[(size_t)(f4 + 1) * 512 + lane * 8];
        acc = MFMA_BF16(ah, bhv, acc);
        acc = MFMA_BF16(al, bhv, acc);
        acc = MFMA_BF16(ah, blv, acc);
    }
    const int oo = w * 16 + l15;
    const float bias = PWb[oo] + NWb[oo];
    float s = 0.f, sq = 0.f;
    #pragma unroll
    for (int r = 0; r < 4; ++r) {
        const float yv = acc[r] + bias;
        y[(size_t)(bi0 + q4 * 4 + r) * O_ + oo] = yv;
        s += yv; sq += yv * yv;
    }
    s  += __shfl_xor(s, 16);  s  += __shfl_xor(s, 32);
    sq += __shfl_xor(sq, 16); sq += __shfl_xor(sq, 32);
    if (q4 == 0) {
        part[bid * 256 + oo]       = s;
        part[bid * 256 + 128 + oo] = sq;
    }
}

// ---------------------------------------------------------------------------
// bn_apply_fused (validated r17-r21): redundant stats reduce + BN + SELU.
// ---------------------------------------------------------------------------
__global__ __launch_bounds__(256) void bn_apply_fused(
    float* __restrict__ y, const float* __restrict__ part,
    const float* __restrict__ gamma, const float* __restrict__ beta)
{
    __shared__ float sStats[128];
    const int tid = threadIdx.x, o = tid & 63, g = tid >> 6;

    float s = 0.f, sq = 0.f;
    #pragma unroll 4
    for (int k = 0; k < 32; ++k) {
        const int blk = g * 32 + k;
        s  += part[blk * 256 + o];
        sq += part[blk * 256 + 128 + o];
    }
    __shared__ float ls[4][64], lq[4][64];
    ls[g][o] = s; lq[g][o] = sq;
    __syncthreads();
    if (tid < 64) {
        const float inv = 1.f / 2048.f;
        const float ts = ls[0][tid] + ls[1][tid] + ls[2][tid] + ls[3][tid];
        const float tq = lq[0][tid] + lq[1][tid] + lq[2][tid] + lq[3][tid];
        const float mu  = ts * inv;
        const float var = tq * inv - mu * mu;
        const float rstd = rsqrtf(var + 1e-5f);
        const float sc = gamma[tid] * rstd;
        sStats[tid]      = sc;
        sStats[64 + tid] = beta[tid] - mu * sc;
    }
    __syncthreads();

    const int idx = blockIdx.x * 256 + tid;
    f32x4 v = *(f32x4*)&y[idx * 4];
    const int o0 = (idx * 4) & 63;
    #pragma unroll
    for (int k = 0; k < 4; ++k) {
        const float t = v[k] * sStats[o0 + k] + sStats[64 + o0 + k];
        v[k] = t > 0.f ? SELU_SCALE * t : SELU_SCALE_ALPHA * (__expf(t) - 1.f);
    }
    *(f32x4*)&y[idx * 4] = v;
}

extern "C" void kernel_launch(void* const* d_in, const int* in_sizes, int n_in,
                              void* d_out, int out_size, void* d_ws, size_t ws_size,
                              hipStream_t stream)
{
    (void)in_sizes; (void)n_in; (void)out_size; (void)ws_size;
    const float* x     = (const float*)d_in[0];
    const float* Wa    = (const float*)d_in[1];
    const float* ba    = (const float*)d_in[2];
    const float* AW    = (const float*)d_in[3];
    const float* PW    = (const float*)d_in[4];
    const float* PWb   = (const float*)d_in[5];
    const float* NW    = (const float*)d_in[6];
    const float* NWb   = (const float*)d_in[7];
    const float* gamma = (const float*)d_in[8];
    const float* beta  = (const float*)d_in[9];

    char* ws = (char*)d_ws;
    ushort* xf    = (ushort*)ws;                                   // 1 MB
    ushort* xfT   = (ushort*)(ws + (1 << 20));                     // 1 MB
    ushort* X1h   = (ushort*)(ws + (2 << 20));                     // 2 MB
    ushort* X1l   = (ushort*)(ws + (4 << 20));                     // 2 MB
    ushort* pwf   = (ushort*)(ws + (6 << 20));                     // 128 KB
    ushort* nwf   = (ushort*)(ws + (6 << 20) + (128 << 10));       // 32 KB
    float*  part  = (float*)(ws + (6 << 20) + (160 << 10));        // 128 KB
    float*  y     = (float*)d_out;

    prep_frags<<<276, 256, 0, stream>>>(x, PW, NW, xf, xfT, pwf, nwf);
    attn_scores<<<dim3(N_, B_), 256, 0, stream>>>(x, xf, xfT, Wa, ba, AW, X1h, X1l);
    proj_y_part<<<128, 256, 0, stream>>>(X1h, X1l, xf, pwf, nwf, PWb, NWb, y, part);
    bn_apply_fused<<<128, 256, 0, stream>>>(y, part, gamma, beta);
}

// Round 23
// 76.955 us; speedup vs baseline: 1.4519x; 1.0249x over previous
//
#include <hip/hip_runtime.h>
#include <hip/hip_bf16.h>
#include <math.h>

#define B_ 4
#define N_ 512
#define D_ 128
#define O_ 64
#define H_ 4

#define SELU_SCALE 1.0507009873554805f
#define SELU_SCALE_ALPHA 1.7580993408473766f  // scale * alpha
#define LOG2E 1.4426950408889634f

typedef short  short8 __attribute__((ext_vector_type(8)));
typedef float  f32x4  __attribute__((ext_vector_type(4)));

__device__ __forceinline__ ushort bf16rne(float f) {
    uint u = __float_as_uint(f);
    return (ushort)((u + 0x7fffu + ((u >> 16) & 1u)) >> 16);
}
__device__ __forceinline__ void bf16split(float f, ushort& h, ushort& l) {
    h = bf16rne(f);
    float hf = __uint_as_float(((uint)h) << 16);
    l = bf16rne(f - hf);
}

// ---------------------------------------------------------------------------
// prep_frags (r23: xfT lo-plane no longer written — dead since r21).
// ---------------------------------------------------------------------------
__global__ __launch_bounds__(256) void prep_frags(
    const float* __restrict__ x, const float* __restrict__ PW,
    const float* __restrict__ NW,
    ushort* __restrict__ xf, ushort* __restrict__ xfT,
    ushort* __restrict__ pwf, ushort* __restrict__ nwf)
{
    const int bid = blockIdx.x;
    const int tid = threadIdx.x;

    if (bid < 128) {
        const int t  = bid * 256 + tid;
        const int jg = t >> 4;
        const int dc = t & 15;
        const int jf = jg >> 4;
        const int kc = dc >> 2, q = dc & 3;
        const int lane = (jg & 15) | (q << 4);

        const f32x4 v0 = *(const f32x4*)&x[t * 8];
        const f32x4 v1 = *(const f32x4*)&x[t * 8 + 4];
        float vv[8] = {v0[0], v0[1], v0[2], v0[3], v1[0], v1[1], v1[2], v1[3]};
        short8 h8, l8;
        #pragma unroll
        for (int e = 0; e < 8; ++e) {
            ushort h, l; bf16split(vv[e], h, l);
            h8[e] = (short)h; l8[e] = (short)l;
        }
        const int fi = (jf * 4 + kc) * 2;
        *(short8*)&xf[(size_t)fi * 512 + lane * 8]       = h8;
        *(short8*)&xf[(size_t)(fi + 1) * 512 + lane * 8] = l8;
    } else if (bid < 256) {
        const int t    = (bid - 128) * 256 + tid;
        const int lane = t & 63, fr = t >> 6;
        const int d0 = fr & 7, kc = (fr >> 3) & 15, b = fr >> 7;
        const int l15 = lane & 15, q4 = lane >> 4;
        short8 h8;
        #pragma unroll
        for (int e = 0; e < 8; ++e) {
            const float v = x[(size_t)((b * 512) + kc * 32 + q4 * 8 + e) * 128 + d0 * 16 + l15];
            h8[e] = (short)bf16rne(v);
        }
        *(short8*)&xfT[(size_t)(fr * 2) * 512 + lane * 8] = h8;   // hi only
    } else if (bid < 272) {
        const int t    = (bid - 256) * 256 + tid;
        const int lane = t & 63, fr = t >> 6;
        const int o0 = fr & 3, kc = fr >> 2;
        const int l15 = lane & 15, q4 = lane >> 4;
        short8 h8, l8;
        #pragma unroll
        for (int e = 0; e < 8; ++e) {
            const int kk = kc * 32 + q4 * 8 + e;
            const int d = kk & 127, h = kk >> 7;
            const float v = PW[(d * 4 + h) * O_ + o0 * 16 + l15];
            ushort hh, ll; bf16split(v, hh, ll);
            h8[e] = (short)hh; l8[e] = (short)ll;
        }
        *(short8*)&pwf[(size_t)(fr * 2) * 512 + lane * 8]     = h8;
        *(short8*)&pwf[(size_t)(fr * 2 + 1) * 512 + lane * 8] = l8;
    } else {
        const int t    = (bid - 272) * 256 + tid;
        const int lane = t & 63, fr = t >> 6;
        const int o0 = fr & 3, kc = fr >> 2;
        const int l15 = lane & 15, q4 = lane >> 4;
        short8 h8, l8;
        #pragma unroll
        for (int e = 0; e < 8; ++e) {
            const float v = NW[(kc * 32 + q4 * 8 + e) * O_ + o0 * 16 + l15];
            ushort hh, ll; bf16split(v, hh, ll);
            h8[e] = (short)hh; l8[e] = (short)ll;
        }
        *(short8*)&nwf[(size_t)(fr * 2) * 512 + lane * 8]     = h8;
        *(short8*)&nwf[(size_t)(fr * 2 + 1) * 512 + lane * 8] = l8;
    }
}

#define SP_STRIDE 520

// compiler-proof 16B global load: UNIFORM SGPR base + per-lane VGPR byte
// offset + imm (r11 post-mortem: base must be wave-uniform for "s").
#define GLD(dst, off, base, IMM)                                     \
    asm volatile("global_load_dwordx4 %0, %1, %2 offset:" #IMM       \
                 : "=v"(dst) : "v"(off), "s"(base))

#define MFMA_BF16(A, Bv, C) __builtin_amdgcn_mfma_f32_16x16x32_bf16(A, Bv, C, 0, 0, 0)

// ---------------------------------------------------------------------------
// attn_scores: r22 phase-1 preserved exactly (passed, 64.6 us). r23:
// (a) P stored as bf16 in LDS (softmax writes ushort; phase-3 P-frag is one
// short8 LDS read, no conversions); (b) X1-lo dropped (single rne + store).
// ---------------------------------------------------------------------------
__global__ __launch_bounds__(256)
__attribute__((amdgpu_waves_per_eu(2, 2)))
void attn_scores(
    const float* __restrict__ x,
    const ushort* __restrict__ xf,
    const ushort* __restrict__ xfT,
    const float* __restrict__ Wa,
    const float* __restrict__ ba,
    const float* __restrict__ AW,
    ushort* __restrict__ X1h)
{
    __shared__ float  sAmp[8 * SP_STRIDE];   // [wo*4+q4][j] logit partials; aliased as sXp
    __shared__ ushort sPb[4 * SP_STRIDE];    // probs [h][j] as bf16

    const int tid  = threadIdx.x;
    const int i    = blockIdx.x;
    const int bB   = blockIdx.y;
    const int lane = tid & 63;
    const int w    = tid >> 6;
    const int l15  = lane & 15;
    const int q4   = lane >> 4;
    const int wo   = w >> 1;                // o-half
    const int wj   = w & 1;                 // j-half
    const f32x4 z = {0.f, 0.f, 0.f, 0.f};

    const ushort* xfb = xf + (size_t)(bB * 32) * 4096;     // block-uniform base
    const uint voff  = (uint)lane * 16u + (uint)wj * 131072u;
    const uint voff2 = voff + 4096u;

    // ---- prologue: issue this wave's tile-0 HI loads immediately ----
    short8 Bh0[4], Bh1[4];
    GLD(Bh0[0], voff,  xfb, 0);    GLD(Bh0[1], voff,  xfb, 2048);
    GLD(Bh0[2], voff2, xfb, 0);    GLD(Bh0[3], voff2, xfb, 2048);

    // ---- A-frags: two G2^T HI rows (2*log2e folded), o = wo*32+l15 / +16 ----
    const float* xi = x + ((size_t)bB * N_ + i) * D_;
    const int oa0 = wo * 32 + l15, oa1 = oa0 + 16;
    short8 gh0[4], gh1[4];
    #pragma unroll
    for (int kc = 0; kc < 4; ++kc) {
        const int d0 = kc * 32 + q4 * 8;
        const f32x4 a0 = *(const f32x4*)&xi[d0];
        const f32x4 a1 = *(const f32x4*)&xi[d0 + 4];
        #pragma unroll
        for (int e = 0; e < 8; ++e) {
            const float xe2 = (2.f * LOG2E) * ((e < 4) ? a0[e & 3] : a1[e & 3]);
            gh0[kc][e] = (short)bf16rne(xe2 * Wa[(d0 + e) * O_ + oa0]);
            gh1[kc][e] = (short)bf16rne(xe2 * Wa[(d0 + e) * O_ + oa1]);
        }
    }

    // ---- epilogue constants: 8 o's per lane (4 per row) ----
    const int oc0 = wo * 32 + q4 * 4, oc1 = oc0 + 16;
    const f32x4 awA0 = *(const f32x4*)&AW[(oc0 + 0) * H_];
    const f32x4 awA1 = *(const f32x4*)&AW[(oc0 + 1) * H_];
    const f32x4 awA2 = *(const f32x4*)&AW[(oc0 + 2) * H_];
    const f32x4 awA3 = *(const f32x4*)&AW[(oc0 + 3) * H_];
    const f32x4 awB0 = *(const f32x4*)&AW[(oc1 + 0) * H_];
    const f32x4 awB1 = *(const f32x4*)&AW[(oc1 + 1) * H_];
    const f32x4 awB2 = *(const f32x4*)&AW[(oc1 + 2) * H_];
    const f32x4 awB3 = *(const f32x4*)&AW[(oc1 + 3) * H_];
    const f32x4 b2A = { (2.f * LOG2E) * ba[oc0], (2.f * LOG2E) * ba[oc0 + 1],
                        (2.f * LOG2E) * ba[oc0 + 2], (2.f * LOG2E) * ba[oc0 + 3] };
    const f32x4 b2B = { (2.f * LOG2E) * ba[oc1], (2.f * LOG2E) * ba[oc1 + 1],
                        (2.f * LOG2E) * ba[oc1 + 2], (2.f * LOG2E) * ba[oc1 + 3] };

// One tile T: issue next tile's 4 HI loads, counted wait, 8 MFMA in two
// chains, tanh via exp2 + am (dual chains), row store. No barriers.
#define SCORE_STEP(BHc, BHn, T)                                                     \
    {                                                                               \
        if ((T) < 15) {                                                             \
            const ushort* bp = xfb + (size_t)((T) + 1) * 4096;                      \
            GLD(BHn[0], voff,  bp, 0);    GLD(BHn[1], voff,  bp, 2048);             \
            GLD(BHn[2], voff2, bp, 0);    GLD(BHn[3], voff2, bp, 2048);             \
            asm volatile("s_waitcnt vmcnt(4)" ::: "memory");                        \
        } else {                                                                    \
            asm volatile("s_waitcnt vmcnt(0)" ::: "memory");                        \
        }                                                                           \
        __builtin_amdgcn_sched_barrier(0);                                          \
        f32x4 accA = b2A, accB = b2B;                                               \
        _Pragma("unroll")                                                           \
        for (int kc = 0; kc < 4; ++kc) {                                            \
            accA = MFMA_BF16(gh0[kc], BHc[kc], accA);                               \
            accB = MFMA_BF16(gh1[kc], BHc[kc], accB);                               \
        }                                                                           \
        f32x4 amA, amB;                                                             \
        {                                                                           \
            const float e0 = exp2f(accA[0]);                                        \
            const float e1 = exp2f(accA[1]);                                        \
            const float e2 = exp2f(accA[2]);                                        \
            const float e3 = exp2f(accA[3]);                                        \
            const float f0 = exp2f(accB[0]);                                        \
            const float f1 = exp2f(accB[1]);                                        \
            const float f2 = exp2f(accB[2]);                                        \
            const float f3 = exp2f(accB[3]);                                        \
            amA  = fmaf(-2.f, __builtin_amdgcn_rcpf(e0 + 1.f), 1.f) * awA0;         \
            amB  = fmaf(-2.f, __builtin_amdgcn_rcpf(f0 + 1.f), 1.f) * awB0;         \
            amA += fmaf(-2.f, __builtin_amdgcn_rcpf(e1 + 1.f), 1.f) * awA1;         \
            amB += fmaf(-2.f, __builtin_amdgcn_rcpf(f1 + 1.f), 1.f) * awB1;         \
            amA += fmaf(-2.f, __builtin_amdgcn_rcpf(e2 + 1.f), 1.f) * awA2;         \
            amB += fmaf(-2.f, __builtin_amdgcn_rcpf(f2 + 1.f), 1.f) * awB2;         \
            amA += fmaf(-2.f, __builtin_amdgcn_rcpf(e3 + 1.f), 1.f) * awA3;         \
            amB += fmaf(-2.f, __builtin_amdgcn_rcpf(f3 + 1.f), 1.f) * awB3;         \
        }                                                                           \
        f32x4 am = amA + amB;                                                       \
        _Pragma("unroll")                                                           \
        for (int k = 0; k < 4; ++k) {                                               \
            am[k] += __shfl_xor(am[k], 16);                                         \
            am[k] += __shfl_xor(am[k], 32);                                         \
        }                                                                           \
        const float amsel = (q4 == 0) ? am[0] : (q4 == 1) ? am[1]                   \
                          : (q4 == 2) ? am[2] : am[3];                              \
        sAmp[(wo * 4 + q4) * SP_STRIDE + (wj * 16 + (T)) * 16 + l15] = amsel;       \
    }

    for (int t = 0; t < 7; ++t) {
        SCORE_STEP(Bh0, Bh1, 2 * t)
        SCORE_STEP(Bh1, Bh0, 2 * t + 1)
    }
    SCORE_STEP(Bh0, Bh1, 14)
    SCORE_STEP(Bh1, Bh0, 15)
#undef SCORE_STEP
    __syncthreads();   // all logit rows visible

    // ---- phase-3 prefetch setup; c=0 HI loads issued NOW, hidden by softmax
    short8 XA[8], XB[8];
    uint offs[8];
    #pragma unroll
    for (int nf = 0; nf < 8; ++nf)
        offs[nf] = (uint)lane * 16u + (uint)w * 65536u + (uint)nf * 2048u;
    {
        const ushort* bp3 = xfT + (size_t)(bB * 16) * 8192;   // c = 0 base
        #pragma unroll
        for (int nf = 0; nf < 8; ++nf) GLD(XA[nf], offs[nf], bp3, 0);
    }

    // ---- phase 2: softmax over j, one wave per head; writes bf16 probs ----
    {
        const int h = w;
        float v[8];
        float m = -INFINITY;
        #pragma unroll
        for (int k = 0; k < 8; ++k) {
            const int j = k * 64 + lane;
            v[k] = sAmp[h * SP_STRIDE + j] + sAmp[(4 + h) * SP_STRIDE + j];
            m = fmaxf(m, v[k]);
        }
        #pragma unroll
        for (int s = 32; s >= 1; s >>= 1) m = fmaxf(m, __shfl_xor(m, s));
        float l = 0.f;
        #pragma unroll
        for (int k = 0; k < 8; ++k) { v[k] = __expf(v[k] - m); l += v[k]; }
        #pragma unroll
        for (int s = 32; s >= 1; s >>= 1) l += __shfl_xor(l, s);
        const float rinv = 1.f / l;
        #pragma unroll
        for (int k = 0; k < 8; ++k)
            sPb[h * SP_STRIDE + k * 64 + lane] = bf16rne(v[k] * rinv);
    }
    __syncthreads();

    // ---- phase 3: x1 = Phi.Xhi via MFMA, GLD-pipelined at c granularity ----
    f32x4 acc2[8];
    #pragma unroll
    for (int nf = 0; nf < 8; ++nf) acc2[nf] = z;

#define P3_STEP(XC, XN, C)                                                          \
    {                                                                               \
        if ((C) < 3) {                                                              \
            const ushort* bp3 = xfT + (size_t)(bB * 16 + (C) + 1) * 8192;           \
            _Pragma("unroll")                                                       \
            for (int nf = 0; nf < 8; ++nf) GLD(XN[nf], offs[nf], bp3, 0);           \
        }                                                                           \
        const int kc = w * 4 + (C);                                                 \
        const short8 pah = *(const short8*)&sPb[(l15 & 3) * SP_STRIDE               \
                                                + kc * 32 + q4 * 8];                \
        if ((C) < 3) { asm volatile("s_waitcnt vmcnt(8)" ::: "memory"); }           \
        else         { asm volatile("s_waitcnt vmcnt(0)" ::: "memory"); }           \
        __builtin_amdgcn_sched_barrier(0);                                          \
        _Pragma("unroll")                                                           \
        for (int nf = 0; nf < 8; ++nf)                                              \
            acc2[nf] = MFMA_BF16(pah, XC[nf], acc2[nf]);                            \
    }

    P3_STEP(XA, XB, 0)
    P3_STEP(XB, XA, 1)
    P3_STEP(XA, XB, 2)
    P3_STEP(XB, XA, 3)
#undef P3_STEP

    float* sXp = sAmp;   // reuse logit rows as [16][128] wave partials
    if (q4 == 0) {
        #pragma unroll
        for (int nf = 0; nf < 8; ++nf)
            #pragma unroll
            for (int r = 0; r < 4; ++r)
                sXp[(w * 4 + r) * 128 + nf * 16 + l15] = acc2[nf][r];
    }
    __syncthreads();

    // ---- phase 3b: reduce wave partials, single-rne, store X1 (hi only) ----
    {
        const int kap = tid * 2;
        const size_t row = (size_t)bB * N_ + i;
        float v0 = 0.f, v1 = 0.f;
        #pragma unroll
        for (int ww = 0; ww < 4; ++ww) {
            v0 += sXp[(ww * 4 + (kap >> 7)) * 128 + (kap & 127)];
            v1 += sXp[(ww * 4 + ((kap + 1) >> 7)) * 128 + ((kap + 1) & 127)];
        }
        const ushort h0 = bf16rne(v0), h1 = bf16rne(v1);
        *(uint*)&X1h[row * 512 + kap] = (uint)h0 | ((uint)h1 << 16);
    }
}

// ---------------------------------------------------------------------------
// proj_y_part: y = x1.PW' + x.NW + biases (MFMA) + per-block BN partial sums.
// r23: X1 is hi-only (2 MFMA per kc in the x1 loop).
// ---------------------------------------------------------------------------
__global__ __launch_bounds__(256) void proj_y_part(
    const ushort* __restrict__ X1h,
    const ushort* __restrict__ xf,
    const ushort* __restrict__ pwf, const ushort* __restrict__ nwf,
    const float* __restrict__ PWb, const float* __restrict__ NWb,
    float* __restrict__ y, float* __restrict__ part)
{
    const int tid = threadIdx.x, bid = blockIdx.x;
    const int lane = tid & 63, w = tid >> 6;
    const int l15 = lane & 15, q4 = lane >> 4;
    const int bi0 = bid * 16;
    const int b = bi0 >> 9, ig = (bi0 >> 4) & 31;

    f32x4 acc = {0.f, 0.f, 0.f, 0.f};
    #pragma unroll
    for (int kc = 0; kc < 16; ++kc) {
        const size_t arow = (size_t)(bi0 + l15) * 512 + kc * 32 + q4 * 8;
        const short8 ah = *(const short8*)&X1h[arow];
        const int f3 = (kc * 4 + w) * 2;
        const short8 bhv = *(const short8*)&pwf[(size_t)f3 * 512 + lane * 8];
        const short8 blv = *(const short8*)&pwf[(size_t)(f3 + 1) * 512 + lane * 8];
        acc = MFMA_BF16(ah, bhv, acc);
        acc = MFMA_BF16(ah, blv, acc);
    }
    #pragma unroll
    for (int kc = 0; kc < 4; ++kc) {
        const size_t fi = ((size_t)(b * 32 + ig) * 4 + kc) * 2;
        const short8 ah = *(const short8*)&xf[fi * 512 + lane * 8];
        const short8 al = *(const short8*)&xf[(fi + 1) * 512 + lane * 8];
        const int f4 = (kc * 4 + w) * 2;
        const short8 bhv = *(const short8*)&nwf[(size_t)f4 * 512 + lane * 8];
        const short8 blv = *(const short8*)&nwf[(size_t)(f4 + 1) * 512 + lane * 8];
        acc = MFMA_BF16(ah, bhv, acc);
        acc = MFMA_BF16(al, bhv, acc);
        acc = MFMA_BF16(ah, blv, acc);
    }
    const int oo = w * 16 + l15;
    const float bias = PWb[oo] + NWb[oo];
    float s = 0.f, sq = 0.f;
    #pragma unroll
    for (int r = 0; r < 4; ++r) {
        const float yv = acc[r] + bias;
        y[(size_t)(bi0 + q4 * 4 + r) * O_ + oo] = yv;
        s += yv; sq += yv * yv;
    }
    s  += __shfl_xor(s, 16);  s  += __shfl_xor(s, 32);
    sq += __shfl_xor(sq, 16); sq += __shfl_xor(sq, 32);
    if (q4 == 0) {
        part[bid * 256 + oo]       = s;
        part[bid * 256 + 128 + oo] = sq;
    }
}

// ---------------------------------------------------------------------------
// bn_apply_fused (validated r17-r22): redundant stats reduce + BN + SELU.
// ---------------------------------------------------------------------------
__global__ __launch_bounds__(256) void bn_apply_fused(
    float* __restrict__ y, const float* __restrict__ part,
    const float* __restrict__ gamma, const float* __restrict__ beta)
{
    __shared__ float sStats[128];
    const int tid = threadIdx.x, o = tid & 63, g = tid >> 6;

    float s = 0.f, sq = 0.f;
    #pragma unroll 4
    for (int k = 0; k < 32; ++k) {
        const int blk = g * 32 + k;
        s  += part[blk * 256 + o];
        sq += part[blk * 256 + 128 + o];
    }
    __shared__ float ls[4][64], lq[4][64];
    ls[g][o] = s; lq[g][o] = sq;
    __syncthreads();
    if (tid < 64) {
        const float inv = 1.f / 2048.f;
        const float ts = ls[0][tid] + ls[1][tid] + ls[2][tid] + ls[3][tid];
        const float tq = lq[0][tid] + lq[1][tid] + lq[2][tid] + lq[3][tid];
        const float mu  = ts * inv;
        const float var = tq * inv - mu * mu;
        const float rstd = rsqrtf(var + 1e-5f);
        const float sc = gamma[tid] * rstd;
        sStats[tid]      = sc;
        sStats[64 + tid] = beta[tid] - mu * sc;
    }
    __syncthreads();

    const int idx = blockIdx.x * 256 + tid;
    f32x4 v = *(f32x4*)&y[idx * 4];
    const int o0 = (idx * 4) & 63;
    #pragma unroll
    for (int k = 0; k < 4; ++k) {
        const float t = v[k] * sStats[o0 + k] + sStats[64 + o0 + k];
        v[k] = t > 0.f ? SELU_SCALE * t : SELU_SCALE_ALPHA * (__expf(t) - 1.f);
    }
    *(f32x4*)&y[idx * 4] = v;
}

extern "C" void kernel_launch(void* const* d_in, const int* in_sizes, int n_in,
                              void* d_out, int out_size, void* d_ws, size_t ws_size,
                              hipStream_t stream)
{
    (void)in_sizes; (void)n_in; (void)out_size; (void)ws_size;
    const float* x     = (const float*)d_in[0];
    const float* Wa    = (const float*)d_in[1];
    const float* ba    = (const float*)d_in[2];
    const float* AW    = (const float*)d_in[3];
    const float* PW    = (const float*)d_in[4];
    const float* PWb   = (const float*)d_in[5];
    const float* NW    = (const float*)d_in[6];
    const float* NWb   = (const float*)d_in[7];
    const float* gamma = (const float*)d_in[8];
    const float* beta  = (const float*)d_in[9];

    char* ws = (char*)d_ws;
    ushort* xf    = (ushort*)ws;                                   // 1 MB
    ushort* xfT   = (ushort*)(ws + (1 << 20));                     // 1 MB (hi only)
    ushort* X1h   = (ushort*)(ws + (2 << 20));                     // 2 MB
    ushort* pwf   = (ushort*)(ws + (6 << 20));                     // 128 KB
    ushort* nwf   = (ushort*)(ws + (6 << 20) + (128 << 10));       // 32 KB
    float*  part  = (float*)(ws + (6 << 20) + (160 << 10));        // 128 KB
    float*  y     = (float*)d_out;

    prep_frags<<<276, 256, 0, stream>>>(x, PW, NW, xf, xfT, pwf, nwf);
    attn_scores<<<dim3(N_, B_), 256, 0, stream>>>(x, xf, xfT, Wa, ba, AW, X1h);
    proj_y_part<<<128, 256, 0, stream>>>(X1h, xf, pwf, nwf, PWb, NWb, y, part);
    bn_apply_fused<<<128, 256, 0, stream>>>(y, part, gamma, beta);
}